// Round 1
// baseline (531.508 us; speedup 1.0000x reference)
//
#include <hip/hip_runtime.h>
#include <hip/hip_bf16.h>

// Problem constants
#define BB 4
#define HH 64
#define WW 64
#define LL 4096           // HH*WW
#define DM 192            // D_MODEL
#define DI 384            // D_INNER
#define NS 16             // D_STATE
#define RK 12             // DT_RANK
#define NC 64             // number of scan chunks
#define CH 64             // chunk length (NC*CH == LL)
#define ROWS 16384        // BB*LL

__device__ __forceinline__ float fsilu(float x) {
    return x / (1.0f + __expf(-x));
}

// ---------------------------------------------------------------------------
// Generic 64x64 tiled f32 GEMM, 256 threads, 4x4 micro-tile.
// SPLIT=true: N=2*halfN, writes col<halfN to C0, col>=halfN to C1 (both halfN-wide).
// ---------------------------------------------------------------------------
template<bool SPLIT>
__global__ __launch_bounds__(256) void gemm_f32_64x64(
    const float* __restrict__ A, const float* __restrict__ B,
    float* __restrict__ C0, float* __restrict__ C1,
    int M, int N, int K, int halfN)
{
    __shared__ float As[16][65];   // padded: avoid 16-way write conflict
    __shared__ float Bs[16][64];
    const int tid = threadIdx.x;
    const int tx = tid & 15, ty = tid >> 4;
    const int row0 = blockIdx.x * 64, col0 = blockIdx.y * 64;
    float acc[4][4] = {};
    for (int k0 = 0; k0 < K; k0 += 16) {
        #pragma unroll
        for (int i = 0; i < 4; ++i) {
            int e = tid + 256 * i;
            int r = e >> 4, kk = e & 15;
            As[kk][r] = A[(row0 + r) * K + k0 + kk];
        }
        #pragma unroll
        for (int i = 0; i < 4; ++i) {
            int e = tid + 256 * i;
            int r = e >> 6, c = e & 63;
            Bs[r][c] = B[(k0 + r) * N + col0 + c];
        }
        __syncthreads();
        #pragma unroll
        for (int kk = 0; kk < 16; ++kk) {
            float a[4], bb[4];
            #pragma unroll
            for (int i = 0; i < 4; ++i) a[i] = As[kk][ty * 4 + i];
            #pragma unroll
            for (int j = 0; j < 4; ++j) bb[j] = Bs[kk][tx * 4 + j];
            #pragma unroll
            for (int i = 0; i < 4; ++i)
                #pragma unroll
                for (int j = 0; j < 4; ++j)
                    acc[i][j] += a[i] * bb[j];
        }
        __syncthreads();
    }
    #pragma unroll
    for (int i = 0; i < 4; ++i) {
        int row = row0 + ty * 4 + i;
        int col = col0 + tx * 4;
        float4 v = make_float4(acc[i][0], acc[i][1], acc[i][2], acc[i][3]);
        if (SPLIT) {
            if (col < halfN) *(float4*)&C0[(size_t)row * halfN + col] = v;
            else             *(float4*)&C1[(size_t)row * halfN + col - halfN] = v;
        } else {
            *(float4*)&C0[(size_t)row * N + col] = v;
        }
    }
}

// ---------------------------------------------------------------------------
// Depthwise 3x3 conv (channel-last), bias + SiLU.  xi: (B,H,W,DI) -> u: (B,L,DI)
// Thread handles 4 channels (one float4) at one (b,h,w).
// ---------------------------------------------------------------------------
__global__ __launch_bounds__(256) void conv_dw_silu(
    const float* __restrict__ xi, const float* __restrict__ conv_w,
    const float* __restrict__ conv_b, float* __restrict__ u)
{
    int idx = blockIdx.x * 256 + threadIdx.x;   // total BB*HH*WW*96
    int c4 = idx % 96;
    int rest = idx / 96;
    int w = rest % WW; rest /= WW;
    int h = rest % HH;
    int b = rest / HH;
    int c = c4 * 4;

    float wgt[4][9];
    #pragma unroll
    for (int q = 0; q < 4; ++q)
        #pragma unroll
        for (int t = 0; t < 9; ++t)
            wgt[q][t] = conv_w[(c + q) * 9 + t];

    float4 acc = *(const float4*)&conv_b[c];
    #pragma unroll
    for (int kh = 0; kh < 3; ++kh) {
        int hh = h + kh - 1;
        if ((unsigned)hh >= HH) continue;
        #pragma unroll
        for (int kw = 0; kw < 3; ++kw) {
            int ww = w + kw - 1;
            if ((unsigned)ww >= WW) continue;
            const float4 xv = *(const float4*)&xi[(((size_t)(b * HH + hh)) * WW + ww) * DI + c];
            int t = kh * 3 + kw;
            acc.x += xv.x * wgt[0][t];
            acc.y += xv.y * wgt[1][t];
            acc.z += xv.z * wgt[2][t];
            acc.w += xv.w * wgt[3][t];
        }
    }
    acc.x = fsilu(acc.x); acc.y = fsilu(acc.y);
    acc.z = fsilu(acc.z); acc.w = fsilu(acc.w);
    *(float4*)&u[(((size_t)b * LL) + h * WW + w) * DI + c] = acc;
}

// ---------------------------------------------------------------------------
// Fused: x_dbl = u @ Wx; delta = softplus(dtr@Wdt + b_dt); Bs; Cs += prompt@Wp.
// One wave per row, 8 rows per wave, 4 waves per block -> 32 rows/block.
// ---------------------------------------------------------------------------
__global__ __launch_bounds__(256) void xdbl_fused(
    const float* __restrict__ u, const float* __restrict__ prompt,
    const float* __restrict__ Wx, const float* __restrict__ Wdt,
    const float* __restrict__ b_dt, const float* __restrict__ Wp,
    float* __restrict__ delta, float* __restrict__ Bsv, float* __restrict__ Csv)
{
    __shared__ float sWx[DI * 44];     // 67584 B
    __shared__ float sWdt[RK * DI];    // 18432 B
    __shared__ float sbdt[DI];         // 1536 B
    __shared__ float su[4][DI];        // 6144 B
    const int tid = threadIdx.x;
    for (int i = tid; i < DI * 44; i += 256) sWx[i] = Wx[i];
    for (int i = tid; i < RK * DI; i += 256) sWdt[i] = Wdt[i];
    for (int i = tid; i < DI; i += 256) sbdt[i] = b_dt[i];
    __syncthreads();

    const int wid = tid >> 6, lane = tid & 63;
    const int rowbase = blockIdx.x * 32 + wid * 8;

    for (int r = 0; r < 8; ++r) {
        const int row = rowbase + r;    // 0..16383
        // stage u row into this wave's LDS slot
        for (int i = lane; i < DI; i += 64) su[wid][i] = u[(size_t)row * DI + i];

        // x_dbl: lane j < 44 computes column j
        float xdbl = 0.f;
        if (lane < 44) {
            float a0 = 0.f, a1 = 0.f, a2 = 0.f, a3 = 0.f;
            for (int k = 0; k < DI; k += 4) {
                a0 += su[wid][k    ] * sWx[(k    ) * 44 + lane];
                a1 += su[wid][k + 1] * sWx[(k + 1) * 44 + lane];
                a2 += su[wid][k + 2] * sWx[(k + 2) * 44 + lane];
                a3 += su[wid][k + 3] * sWx[(k + 3) * 44 + lane];
            }
            xdbl = (a0 + a1) + (a2 + a3);
        }

        // prompt @ Wp: lane = g*16+n; g-partials over c, reduce over g
        const int n = lane & 15, g = lane >> 4;
        const float* prow = prompt + (size_t)row * DM;
        float pw = 0.f;
        for (int cc = g * 48; cc < g * 48 + 48; ++cc)
            pw += prow[cc] * Wp[cc * NS + n];
        pw += __shfl_xor(pw, 16);
        pw += __shfl_xor(pw, 32);   // lanes 0..15 hold full prompt@Wp[n]

        const size_t rb = (size_t)row * NS;
        if (lane >= 12 && lane < 28) Bsv[rb + lane - 12] = xdbl;
        int src = (lane >= 28 && lane < 44) ? (lane - 28) : 0;
        float pwn = __shfl(pw, src);
        if (lane >= 28 && lane < 44) Csv[rb + lane - 28] = xdbl + pwn;

        // delta: broadcast dtr (lanes 0..11), each lane computes 6 channels
        float dtr[RK];
        #pragma unroll
        for (int rr = 0; rr < RK; ++rr) dtr[rr] = __shfl(xdbl, rr);
        #pragma unroll
        for (int jj = 0; jj < 6; ++jj) {
            int dch = jj * 64 + lane;
            float acc = sbdt[dch];
            #pragma unroll
            for (int rr = 0; rr < RK; ++rr) acc += dtr[rr] * sWdt[rr * DI + dch];
            float sp = (acc > 20.f) ? acc : log1pf(__expf(acc));
            delta[(size_t)row * DI + dch] = sp;
        }
    }
}

// ---------------------------------------------------------------------------
// Scan phase 1: per-chunk local scan from h=0 -> (prod a, h_out)
// block: 256 = 16 d x 16 n; grid: BB * NC * (DI/16)
// ---------------------------------------------------------------------------
__global__ __launch_bounds__(256) void scan_p1(
    const float* __restrict__ delta, const float* __restrict__ u,
    const float* __restrict__ Bsv, const float* __restrict__ A_log,
    float* __restrict__ Aprod, float* __restrict__ Hout)
{
    int bid = blockIdx.x;
    int dg = bid % (DI / 16);
    int c  = (bid / (DI / 16)) % NC;
    int b  = bid / ((DI / 16) * NC);
    int tid = threadIdx.x;
    int dl = tid >> 4, n = tid & 15;
    int d = dg * 16 + dl;
    float Adn = -__expf(A_log[d * NS + n]);
    float h = 0.f, ap = 1.f;
    int lbase = c * CH;
    for (int i = 0; i < CH; ++i) {
        int l = lbase + i;
        size_t off = ((size_t)(b * LL + l)) * DI + d;
        float dlt = delta[off];
        float uu  = u[off];
        float bs  = Bsv[(size_t)(b * LL + l) * NS + n];
        float a = __expf(dlt * Adn);
        h = a * h + (dlt * uu) * bs;
        ap *= a;
    }
    size_t idx = (((size_t)(b * NC + c)) * DI + d) * NS + n;
    Aprod[idx] = ap;
    Hout[idx]  = h;
}

// ---------------------------------------------------------------------------
// Scan phase 2: sequential over chunks per (b,d,n) chain.  24576 threads.
// ---------------------------------------------------------------------------
__global__ __launch_bounds__(256) void scan_p2(
    const float* __restrict__ Aprod, const float* __restrict__ Hout,
    float* __restrict__ Hin)
{
    int gid = blockIdx.x * 256 + threadIdx.x;   // (b*DI + d)*NS + n
    int n = gid & 15;
    int d = (gid >> 4) % DI;
    int b = gid / (DI * NS);
    float hin = 0.f;
    for (int c = 0; c < NC; ++c) {
        size_t idx = (((size_t)(b * NC + c)) * DI + d) * NS + n;
        Hin[idx] = hin;
        hin = Aprod[idx] * hin + Hout[idx];
    }
}

// ---------------------------------------------------------------------------
// Scan phase 3: re-scan chunk from true h_in, emit y = h.C + u*D
// ---------------------------------------------------------------------------
__global__ __launch_bounds__(256) void scan_p3(
    const float* __restrict__ delta, const float* __restrict__ u,
    const float* __restrict__ Bsv, const float* __restrict__ Csv,
    const float* __restrict__ Hin, const float* __restrict__ A_log,
    const float* __restrict__ Dvec, float* __restrict__ y)
{
    int bid = blockIdx.x;
    int dg = bid % (DI / 16);
    int c  = (bid / (DI / 16)) % NC;
    int b  = bid / ((DI / 16) * NC);
    int tid = threadIdx.x;
    int dl = tid >> 4, n = tid & 15;
    int d = dg * 16 + dl;
    float Adn = -__expf(A_log[d * NS + n]);
    float Dd = Dvec[d];
    float h = Hin[(((size_t)(b * NC + c)) * DI + d) * NS + n];
    int lbase = c * CH;
    for (int i = 0; i < CH; ++i) {
        int l = lbase + i;
        size_t off = ((size_t)(b * LL + l)) * DI + d;
        float dlt = delta[off];
        float uu  = u[off];
        size_t bcoff = (size_t)(b * LL + l) * NS + n;
        float bs = Bsv[bcoff];
        float cs = Csv[bcoff];
        float a = __expf(dlt * Adn);
        h = a * h + (dlt * uu) * bs;
        float p = h * cs;
        p += __shfl_xor(p, 1);
        p += __shfl_xor(p, 2);
        p += __shfl_xor(p, 4);
        p += __shfl_xor(p, 8);
        if (n == 0) y[off] = p + uu * Dd;
    }
}

// ---------------------------------------------------------------------------
// LayerNorm over d (384) + SiLU(z) gating.  One wave per row.
// ---------------------------------------------------------------------------
__global__ __launch_bounds__(256) void ln_gate(
    const float* __restrict__ y, const float* __restrict__ z,
    const float* __restrict__ ln_g, const float* __restrict__ ln_b,
    float* __restrict__ yin)
{
    int wid = threadIdx.x >> 6, lane = threadIdx.x & 63;
    int row = blockIdx.x * 4 + wid;
    float v[6];
    float s = 0.f, sq = 0.f;
    #pragma unroll
    for (int i = 0; i < 6; ++i) {
        v[i] = y[(size_t)row * DI + i * 64 + lane];
        s += v[i];
        sq += v[i] * v[i];
    }
    #pragma unroll
    for (int m = 1; m < 64; m <<= 1) {
        s  += __shfl_xor(s, m);
        sq += __shfl_xor(sq, m);
    }
    float mu = s * (1.f / DI);
    float var = sq * (1.f / DI) - mu * mu;
    float inv = rsqrtf(var + 1e-5f);
    #pragma unroll
    for (int i = 0; i < 6; ++i) {
        int dch = i * 64 + lane;
        float yn = (v[i] - mu) * inv * ln_g[dch] + ln_b[dch];
        float zz = z[(size_t)row * DI + dch];
        yin[(size_t)row * DI + dch] = yn * fsilu(zz);
    }
}

// ---------------------------------------------------------------------------
extern "C" void kernel_launch(void* const* d_in, const int* in_sizes, int n_in,
                              void* d_out, int out_size, void* d_ws, size_t ws_size,
                              hipStream_t stream)
{
    const float* x      = (const float*)d_in[0];
    const float* prompt = (const float*)d_in[1];
    const float* W_in   = (const float*)d_in[2];
    const float* conv_w = (const float*)d_in[3];
    const float* conv_b = (const float*)d_in[4];
    const float* Wx     = (const float*)d_in[5];
    const float* Wdt    = (const float*)d_in[6];
    const float* b_dt   = (const float*)d_in[7];
    const float* A_log  = (const float*)d_in[8];
    const float* Dvec   = (const float*)d_in[9];
    const float* Wp     = (const float*)d_in[10];
    const float* ln_g   = (const float*)d_in[11];
    const float* ln_b   = (const float*)d_in[12];
    const float* Wout   = (const float*)d_in[13];
    float* out = (float*)d_out;

    char* ws = (char*)d_ws;
    const size_t SZ_BLD = (size_t)ROWS * DI * 4;   // 25165824 B
    float* xi    = (float*)(ws);
    float* z     = (float*)(ws + SZ_BLD);
    float* u     = (float*)(ws + 2 * SZ_BLD);
    float* delta = (float*)(ws + 3 * SZ_BLD);
    float* y     = (float*)(ws + 4 * SZ_BLD);
    char*  p     = ws + 5 * SZ_BLD;
    float* Bsv   = (float*)p;            p += (size_t)ROWS * NS * 4;      // 1 MB
    float* Csv   = (float*)p;            p += (size_t)ROWS * NS * 4;
    float* Aprod = (float*)p;            p += (size_t)BB * NC * DI * NS * 4;  // 6.29 MB
    float* Hout  = (float*)p;            p += (size_t)BB * NC * DI * NS * 4;
    float* Hin   = (float*)p;            p += (size_t)BB * NC * DI * NS * 4;
    float* yin   = xi;   // xi dead after conv

    // 1. xz = x @ W_in, split -> xi, z
    {
        dim3 g(ROWS / 64, 768 / 64);
        gemm_f32_64x64<true><<<g, 256, 0, stream>>>(x, W_in, xi, z, ROWS, 768, DM, DI);
    }
    // 2. depthwise conv + bias + SiLU -> u
    conv_dw_silu<<<(BB * HH * WW * 96) / 256, 256, 0, stream>>>(xi, conv_w, conv_b, u);
    // 3. fused projections -> delta, Bs, Cs
    xdbl_fused<<<ROWS / 32, 256, 0, stream>>>(u, prompt, Wx, Wdt, b_dt, Wp, delta, Bsv, Csv);
    // 4-6. chunked selective scan
    scan_p1<<<BB * NC * (DI / 16), 256, 0, stream>>>(delta, u, Bsv, A_log, Aprod, Hout);
    scan_p2<<<(BB * DI * NS) / 256, 256, 0, stream>>>(Aprod, Hout, Hin);
    scan_p3<<<BB * NC * (DI / 16), 256, 0, stream>>>(delta, u, Bsv, Csv, Hin, A_log, Dvec, y);
    // 7. LayerNorm + SiLU(z) gate -> yin (reuses xi)
    ln_gate<<<ROWS / 4, 256, 0, stream>>>(y, z, ln_g, ln_b, yin);
    // 8. out = yin @ Wout
    {
        dim3 g(ROWS / 64, DM / 64);
        gemm_f32_64x64<false><<<g, 256, 0, stream>>>(yin, Wout, out, nullptr, ROWS, DM, DI, 0);
    }
}

// Round 2
// 493.612 us; speedup vs baseline: 1.0768x; 1.0768x over previous
//
#include <hip/hip_runtime.h>
#include <hip/hip_bf16.h>

// Problem constants
#define BB 4
#define HH 64
#define WW 64
#define LL 4096           // HH*WW
#define DM 192            // D_MODEL
#define DI 384            // D_INNER
#define NS 16             // D_STATE
#define RK 12             // DT_RANK
#define NC 64             // number of scan chunks
#define CH 64             // chunk length (NC*CH == LL)
#define ROWS 16384        // BB*LL

__device__ __forceinline__ float fsilu(float x) {
    return x / (1.0f + __expf(-x));
}

// ---------------------------------------------------------------------------
// Generic 64x64 tiled f32 GEMM, 256 threads, 4x4 micro-tile.
// SPLIT=true: N=2*halfN, writes col<halfN to C0, col>=halfN to C1 (both halfN-wide).
// ---------------------------------------------------------------------------
template<bool SPLIT>
__global__ __launch_bounds__(256) void gemm_f32_64x64(
    const float* __restrict__ A, const float* __restrict__ B,
    float* __restrict__ C0, float* __restrict__ C1,
    int M, int N, int K, int halfN)
{
    __shared__ float As[16][65];   // padded: avoid 16-way write conflict
    __shared__ float Bs[16][64];
    const int tid = threadIdx.x;
    const int tx = tid & 15, ty = tid >> 4;
    const int row0 = blockIdx.x * 64, col0 = blockIdx.y * 64;
    float acc[4][4] = {};
    for (int k0 = 0; k0 < K; k0 += 16) {
        #pragma unroll
        for (int i = 0; i < 4; ++i) {
            int e = tid + 256 * i;
            int r = e >> 4, kk = e & 15;
            As[kk][r] = A[(row0 + r) * K + k0 + kk];
        }
        #pragma unroll
        for (int i = 0; i < 4; ++i) {
            int e = tid + 256 * i;
            int r = e >> 6, c = e & 63;
            Bs[r][c] = B[(k0 + r) * N + col0 + c];
        }
        __syncthreads();
        #pragma unroll
        for (int kk = 0; kk < 16; ++kk) {
            float a[4], bb[4];
            #pragma unroll
            for (int i = 0; i < 4; ++i) a[i] = As[kk][ty * 4 + i];
            #pragma unroll
            for (int j = 0; j < 4; ++j) bb[j] = Bs[kk][tx * 4 + j];
            #pragma unroll
            for (int i = 0; i < 4; ++i)
                #pragma unroll
                for (int j = 0; j < 4; ++j)
                    acc[i][j] += a[i] * bb[j];
        }
        __syncthreads();
    }
    #pragma unroll
    for (int i = 0; i < 4; ++i) {
        int row = row0 + ty * 4 + i;
        int col = col0 + tx * 4;
        float4 v = make_float4(acc[i][0], acc[i][1], acc[i][2], acc[i][3]);
        if (SPLIT) {
            if (col < halfN) *(float4*)&C0[(size_t)row * halfN + col] = v;
            else             *(float4*)&C1[(size_t)row * halfN + col - halfN] = v;
        } else {
            *(float4*)&C0[(size_t)row * N + col] = v;
        }
    }
}

// ---------------------------------------------------------------------------
// Depthwise 3x3 conv (channel-last), bias + SiLU.  xi: (B,H,W,DI) -> u: (B,L,DI)
// Thread handles 4 channels (one float4) at one (b,h,w).
// ---------------------------------------------------------------------------
__global__ __launch_bounds__(256) void conv_dw_silu(
    const float* __restrict__ xi, const float* __restrict__ conv_w,
    const float* __restrict__ conv_b, float* __restrict__ u)
{
    int idx = blockIdx.x * 256 + threadIdx.x;   // total BB*HH*WW*96
    int c4 = idx % 96;
    int rest = idx / 96;
    int w = rest % WW; rest /= WW;
    int h = rest % HH;
    int b = rest / HH;
    int c = c4 * 4;

    float wgt[4][9];
    #pragma unroll
    for (int q = 0; q < 4; ++q)
        #pragma unroll
        for (int t = 0; t < 9; ++t)
            wgt[q][t] = conv_w[(c + q) * 9 + t];

    float4 acc = *(const float4*)&conv_b[c];
    #pragma unroll
    for (int kh = 0; kh < 3; ++kh) {
        int hh = h + kh - 1;
        if ((unsigned)hh >= HH) continue;
        #pragma unroll
        for (int kw = 0; kw < 3; ++kw) {
            int ww = w + kw - 1;
            if ((unsigned)ww >= WW) continue;
            const float4 xv = *(const float4*)&xi[(((size_t)(b * HH + hh)) * WW + ww) * DI + c];
            int t = kh * 3 + kw;
            acc.x += xv.x * wgt[0][t];
            acc.y += xv.y * wgt[1][t];
            acc.z += xv.z * wgt[2][t];
            acc.w += xv.w * wgt[3][t];
        }
    }
    acc.x = fsilu(acc.x); acc.y = fsilu(acc.y);
    acc.z = fsilu(acc.z); acc.w = fsilu(acc.w);
    *(float4*)&u[(((size_t)b * LL) + h * WW + w) * DI + c] = acc;
}

// ---------------------------------------------------------------------------
// Fused projections v2: one ROW per WAVE, zero LDS (weights are L2-resident).
//   x_dbl = u_row @ Wx (44 cols, lanes 0..43)
//   Bs    = x_dbl[12..27]
//   Cs    = x_dbl[28..43] + prompt_row @ Wp
//   delta = softplus(dtr @ Wdt + b_dt)   (dtr = x_dbl[0..11], bcast via shfl)
// Grid: ROWS/4 blocks of 256 (4 waves).
// ---------------------------------------------------------------------------
__global__ __launch_bounds__(256) void xdbl_fused_v2(
    const float* __restrict__ u, const float* __restrict__ prompt,
    const float* __restrict__ Wx, const float* __restrict__ Wdt,
    const float* __restrict__ b_dt, const float* __restrict__ Wp,
    float* __restrict__ delta, float* __restrict__ Bsv, float* __restrict__ Csv)
{
    const int tid = threadIdx.x;
    const int wid = tid >> 6, lane = tid & 63;
    const int row = blockIdx.x * 4 + wid;   // 0..16383

    const float* urow = u + (size_t)row * DI;

    // ---- x_dbl: lane j < 44 computes column j (u row loads are wave-uniform
    // float4 broadcasts; Wx loads are lane-coalesced 176B) ----
    float a0 = 0.f, a1 = 0.f, a2 = 0.f, a3 = 0.f;
    if (lane < 44) {
        for (int k = 0; k < DI; k += 4) {
            const float4 u4 = *(const float4*)&urow[k];
            a0 += u4.x * Wx[(k    ) * 44 + lane];
            a1 += u4.y * Wx[(k + 1) * 44 + lane];
            a2 += u4.z * Wx[(k + 2) * 44 + lane];
            a3 += u4.w * Wx[(k + 3) * 44 + lane];
        }
    }
    const float xdbl = (a0 + a1) + (a2 + a3);

    // ---- prompt @ Wp: lane = g*16+n; each g covers 48 of the 192 c's ----
    const int n16 = lane & 15, g = lane >> 4;
    const float* prow = prompt + (size_t)row * DM;
    float pw = 0.f;
    #pragma unroll
    for (int cc = 0; cc < 48; ++cc) {
        int c = g * 48 + cc;
        pw += prow[c] * Wp[c * NS + n16];
    }
    pw += __shfl_xor(pw, 16);
    pw += __shfl_xor(pw, 32);   // now every lane holds full sum for n = lane&15

    // ---- Bs / Cs stores ----
    const size_t rb = (size_t)row * NS;
    if (lane >= 12 && lane < 28) Bsv[rb + lane - 12] = xdbl;
    int src = (lane >= 28 && lane < 44) ? (lane - 28) : 0;
    float pwn = __shfl(pw, src);             // pw for n = lane-28
    if (lane >= 28 && lane < 44) Csv[rb + lane - 28] = xdbl + pwn;

    // ---- delta: broadcast dtr (cols 0..11), each lane does 6 channels ----
    float dtr[RK];
    #pragma unroll
    for (int r = 0; r < RK; ++r) dtr[r] = __shfl(xdbl, r);
    #pragma unroll
    for (int jj = 0; jj < 6; ++jj) {
        int dch = jj * 64 + lane;
        float acc = b_dt[dch];
        #pragma unroll
        for (int r = 0; r < RK; ++r) acc += dtr[r] * Wdt[r * DI + dch];
        delta[(size_t)row * DI + dch] = (acc > 20.f) ? acc : log1pf(__expf(acc));
    }
}

// ---------------------------------------------------------------------------
// Scan phase 1: per-chunk local scan from h=0 -> (prod a, h_out)
// block: 256 = 16 d x 16 n; grid: BB * NC * (DI/16)
// ---------------------------------------------------------------------------
__global__ __launch_bounds__(256) void scan_p1(
    const float* __restrict__ delta, const float* __restrict__ u,
    const float* __restrict__ Bsv, const float* __restrict__ A_log,
    float* __restrict__ Aprod, float* __restrict__ Hout)
{
    int bid = blockIdx.x;
    int dg = bid % (DI / 16);
    int c  = (bid / (DI / 16)) % NC;
    int b  = bid / ((DI / 16) * NC);
    int tid = threadIdx.x;
    int dl = tid >> 4, n = tid & 15;
    int d = dg * 16 + dl;
    float Adn = -__expf(A_log[d * NS + n]);
    float h = 0.f, ap = 1.f;
    int lbase = c * CH;
    for (int i = 0; i < CH; ++i) {
        int l = lbase + i;
        size_t off = ((size_t)(b * LL + l)) * DI + d;
        float dlt = delta[off];
        float uu  = u[off];
        float bs  = Bsv[(size_t)(b * LL + l) * NS + n];
        float a = __expf(dlt * Adn);
        h = a * h + (dlt * uu) * bs;
        ap *= a;
    }
    size_t idx = (((size_t)(b * NC + c)) * DI + d) * NS + n;
    Aprod[idx] = ap;
    Hout[idx]  = h;
}

// ---------------------------------------------------------------------------
// Scan phase 2: sequential over chunks per (b,d,n) chain.  24576 threads.
// ---------------------------------------------------------------------------
__global__ __launch_bounds__(256) void scan_p2(
    const float* __restrict__ Aprod, const float* __restrict__ Hout,
    float* __restrict__ Hin)
{
    int gid = blockIdx.x * 256 + threadIdx.x;   // (b*DI + d)*NS + n
    int n = gid & 15;
    int d = (gid >> 4) % DI;
    int b = gid / (DI * NS);
    float hin = 0.f;
    for (int c = 0; c < NC; ++c) {
        size_t idx = (((size_t)(b * NC + c)) * DI + d) * NS + n;
        Hin[idx] = hin;
        hin = Aprod[idx] * hin + Hout[idx];
    }
}

// ---------------------------------------------------------------------------
// Scan phase 3: re-scan chunk from true h_in, emit y = h.C + u*D
// ---------------------------------------------------------------------------
__global__ __launch_bounds__(256) void scan_p3(
    const float* __restrict__ delta, const float* __restrict__ u,
    const float* __restrict__ Bsv, const float* __restrict__ Csv,
    const float* __restrict__ Hin, const float* __restrict__ A_log,
    const float* __restrict__ Dvec, float* __restrict__ y)
{
    int bid = blockIdx.x;
    int dg = bid % (DI / 16);
    int c  = (bid / (DI / 16)) % NC;
    int b  = bid / ((DI / 16) * NC);
    int tid = threadIdx.x;
    int dl = tid >> 4, n = tid & 15;
    int d = dg * 16 + dl;
    float Adn = -__expf(A_log[d * NS + n]);
    float Dd = Dvec[d];
    float h = Hin[(((size_t)(b * NC + c)) * DI + d) * NS + n];
    int lbase = c * CH;
    for (int i = 0; i < CH; ++i) {
        int l = lbase + i;
        size_t off = ((size_t)(b * LL + l)) * DI + d;
        float dlt = delta[off];
        float uu  = u[off];
        size_t bcoff = (size_t)(b * LL + l) * NS + n;
        float bs = Bsv[bcoff];
        float cs = Csv[bcoff];
        float a = __expf(dlt * Adn);
        h = a * h + (dlt * uu) * bs;
        float p = h * cs;
        p += __shfl_xor(p, 1);
        p += __shfl_xor(p, 2);
        p += __shfl_xor(p, 4);
        p += __shfl_xor(p, 8);
        if (n == 0) y[off] = p + uu * Dd;
    }
}

// ---------------------------------------------------------------------------
// LayerNorm over d (384) + SiLU(z) gating.  One wave per row.
// ---------------------------------------------------------------------------
__global__ __launch_bounds__(256) void ln_gate(
    const float* __restrict__ y, const float* __restrict__ z,
    const float* __restrict__ ln_g, const float* __restrict__ ln_b,
    float* __restrict__ yin)
{
    int wid = threadIdx.x >> 6, lane = threadIdx.x & 63;
    int row = blockIdx.x * 4 + wid;
    float v[6];
    float s = 0.f, sq = 0.f;
    #pragma unroll
    for (int i = 0; i < 6; ++i) {
        v[i] = y[(size_t)row * DI + i * 64 + lane];
        s += v[i];
        sq += v[i] * v[i];
    }
    #pragma unroll
    for (int m = 1; m < 64; m <<= 1) {
        s  += __shfl_xor(s, m);
        sq += __shfl_xor(sq, m);
    }
    float mu = s * (1.f / DI);
    float var = sq * (1.f / DI) - mu * mu;
    float inv = rsqrtf(var + 1e-5f);
    #pragma unroll
    for (int i = 0; i < 6; ++i) {
        int dch = i * 64 + lane;
        float yn = (v[i] - mu) * inv * ln_g[dch] + ln_b[dch];
        float zz = z[(size_t)row * DI + dch];
        yin[(size_t)row * DI + dch] = yn * fsilu(zz);
    }
}

// ---------------------------------------------------------------------------
extern "C" void kernel_launch(void* const* d_in, const int* in_sizes, int n_in,
                              void* d_out, int out_size, void* d_ws, size_t ws_size,
                              hipStream_t stream)
{
    const float* x      = (const float*)d_in[0];
    const float* prompt = (const float*)d_in[1];
    const float* W_in   = (const float*)d_in[2];
    const float* conv_w = (const float*)d_in[3];
    const float* conv_b = (const float*)d_in[4];
    const float* Wx     = (const float*)d_in[5];
    const float* Wdt    = (const float*)d_in[6];
    const float* b_dt   = (const float*)d_in[7];
    const float* A_log  = (const float*)d_in[8];
    const float* Dvec   = (const float*)d_in[9];
    const float* Wp     = (const float*)d_in[10];
    const float* ln_g   = (const float*)d_in[11];
    const float* ln_b   = (const float*)d_in[12];
    const float* Wout   = (const float*)d_in[13];
    float* out = (float*)d_out;

    char* ws = (char*)d_ws;
    const size_t SZ_BLD = (size_t)ROWS * DI * 4;   // 25165824 B
    float* xi    = (float*)(ws);
    float* z     = (float*)(ws + SZ_BLD);
    float* u     = (float*)(ws + 2 * SZ_BLD);
    float* delta = (float*)(ws + 3 * SZ_BLD);
    float* y     = (float*)(ws + 4 * SZ_BLD);
    char*  p     = ws + 5 * SZ_BLD;
    float* Bsv   = (float*)p;            p += (size_t)ROWS * NS * 4;      // 1 MB
    float* Csv   = (float*)p;            p += (size_t)ROWS * NS * 4;
    float* Aprod = (float*)p;            p += (size_t)BB * NC * DI * NS * 4;  // 6.29 MB
    float* Hout  = (float*)p;            p += (size_t)BB * NC * DI * NS * 4;
    float* Hin   = (float*)p;            p += (size_t)BB * NC * DI * NS * 4;
    float* yin   = xi;   // xi dead after conv

    // 1. xz = x @ W_in, split -> xi, z
    {
        dim3 g(ROWS / 64, 768 / 64);
        gemm_f32_64x64<true><<<g, 256, 0, stream>>>(x, W_in, xi, z, ROWS, 768, DM, DI);
    }
    // 2. depthwise conv + bias + SiLU -> u
    conv_dw_silu<<<(BB * HH * WW * 96) / 256, 256, 0, stream>>>(xi, conv_w, conv_b, u);
    // 3. fused projections -> delta, Bs, Cs  (v2: 1 row/wave, no LDS)
    xdbl_fused_v2<<<ROWS / 4, 256, 0, stream>>>(u, prompt, Wx, Wdt, b_dt, Wp, delta, Bsv, Csv);
    // 4-6. chunked selective scan
    scan_p1<<<BB * NC * (DI / 16), 256, 0, stream>>>(delta, u, Bsv, A_log, Aprod, Hout);
    scan_p2<<<(BB * DI * NS) / 256, 256, 0, stream>>>(Aprod, Hout, Hin);
    scan_p3<<<BB * NC * (DI / 16), 256, 0, stream>>>(delta, u, Bsv, Csv, Hin, A_log, Dvec, y);
    // 7. LayerNorm + SiLU(z) gate -> yin (reuses xi)
    ln_gate<<<ROWS / 4, 256, 0, stream>>>(y, z, ln_g, ln_b, yin);
    // 8. out = yin @ Wout
    {
        dim3 g(ROWS / 64, DM / 64);
        gemm_f32_64x64<false><<<g, 256, 0, stream>>>(yin, Wout, out, nullptr, ROWS, DM, DI, 0);
    }
}

// Round 3
// 448.366 us; speedup vs baseline: 1.1854x; 1.1009x over previous
//
#include <hip/hip_runtime.h>
#include <hip/hip_bf16.h>

// Problem constants
#define BB 4
#define HH 64
#define WW 64
#define LL 4096           // HH*WW
#define DM 192            // D_MODEL
#define DI 384            // D_INNER
#define NS 16             // D_STATE
#define RK 12             // DT_RANK
#define NC 64             // number of scan chunks
#define CH 64             // chunk length (NC*CH == LL)
#define ROWS 16384        // BB*LL
#define XDS 64            // xdbl row stride (44 cols padded to 64)

__device__ __forceinline__ float fsilu(float x) {
    return x / (1.0f + __expf(-x));
}

// ---------------------------------------------------------------------------
// Generic 64x64 tiled f32 GEMM, 256 threads, 4x4 micro-tile.
// SPLIT=true: N=2*halfN, writes col<halfN to C0, col>=halfN to C1 (both halfN-wide).
// ---------------------------------------------------------------------------
template<bool SPLIT>
__global__ __launch_bounds__(256) void gemm_f32_64x64(
    const float* __restrict__ A, const float* __restrict__ B,
    float* __restrict__ C0, float* __restrict__ C1,
    int M, int N, int K, int halfN)
{
    __shared__ float As[16][65];   // padded: avoid 16-way write conflict
    __shared__ float Bs[16][64];
    const int tid = threadIdx.x;
    const int tx = tid & 15, ty = tid >> 4;
    const int row0 = blockIdx.x * 64, col0 = blockIdx.y * 64;
    float acc[4][4] = {};
    for (int k0 = 0; k0 < K; k0 += 16) {
        #pragma unroll
        for (int i = 0; i < 4; ++i) {
            int e = tid + 256 * i;
            int r = e >> 4, kk = e & 15;
            As[kk][r] = A[(row0 + r) * K + k0 + kk];
        }
        #pragma unroll
        for (int i = 0; i < 4; ++i) {
            int e = tid + 256 * i;
            int r = e >> 6, c = e & 63;
            Bs[r][c] = B[(k0 + r) * N + col0 + c];
        }
        __syncthreads();
        #pragma unroll
        for (int kk = 0; kk < 16; ++kk) {
            float a[4], bb[4];
            #pragma unroll
            for (int i = 0; i < 4; ++i) a[i] = As[kk][ty * 4 + i];
            #pragma unroll
            for (int j = 0; j < 4; ++j) bb[j] = Bs[kk][tx * 4 + j];
            #pragma unroll
            for (int i = 0; i < 4; ++i)
                #pragma unroll
                for (int j = 0; j < 4; ++j)
                    acc[i][j] += a[i] * bb[j];
        }
        __syncthreads();
    }
    #pragma unroll
    for (int i = 0; i < 4; ++i) {
        int row = row0 + ty * 4 + i;
        int col = col0 + tx * 4;
        float4 v = make_float4(acc[i][0], acc[i][1], acc[i][2], acc[i][3]);
        if (SPLIT) {
            if (col < halfN) *(float4*)&C0[(size_t)row * halfN + col] = v;
            else             *(float4*)&C1[(size_t)row * halfN + col - halfN] = v;
        } else {
            *(float4*)&C0[(size_t)row * N + col] = v;
        }
    }
}

// ---------------------------------------------------------------------------
// Depthwise 3x3 conv (channel-last), bias + SiLU.  xi: (B,H,W,DI) -> u: (B,L,DI)
// ---------------------------------------------------------------------------
__global__ __launch_bounds__(256) void conv_dw_silu(
    const float* __restrict__ xi, const float* __restrict__ conv_w,
    const float* __restrict__ conv_b, float* __restrict__ u)
{
    int idx = blockIdx.x * 256 + threadIdx.x;   // total BB*HH*WW*96
    int c4 = idx % 96;
    int rest = idx / 96;
    int w = rest % WW; rest /= WW;
    int h = rest % HH;
    int b = rest / HH;
    int c = c4 * 4;

    float wgt[4][9];
    #pragma unroll
    for (int q = 0; q < 4; ++q)
        #pragma unroll
        for (int t = 0; t < 9; ++t)
            wgt[q][t] = conv_w[(c + q) * 9 + t];

    float4 acc = *(const float4*)&conv_b[c];
    #pragma unroll
    for (int kh = 0; kh < 3; ++kh) {
        int hh = h + kh - 1;
        if ((unsigned)hh >= HH) continue;
        #pragma unroll
        for (int kw = 0; kw < 3; ++kw) {
            int ww = w + kw - 1;
            if ((unsigned)ww >= WW) continue;
            const float4 xv = *(const float4*)&xi[(((size_t)(b * HH + hh)) * WW + ww) * DI + c];
            int t = kh * 3 + kw;
            acc.x += xv.x * wgt[0][t];
            acc.y += xv.y * wgt[1][t];
            acc.z += xv.z * wgt[2][t];
            acc.w += xv.w * wgt[3][t];
        }
    }
    acc.x = fsilu(acc.x); acc.y = fsilu(acc.y);
    acc.z = fsilu(acc.z); acc.w = fsilu(acc.w);
    *(float4*)&u[(((size_t)b * LL) + h * WW + w) * DI + c] = acc;
}

// ---------------------------------------------------------------------------
// WxPad: (384 x 44) -> (384 x 64), cols 44..63 = 0
// ---------------------------------------------------------------------------
__global__ __launch_bounds__(256) void build_wxpad(
    const float* __restrict__ Wx, float* __restrict__ WxPad)
{
    int idx = blockIdx.x * 256 + threadIdx.x;   // 384*64
    int k = idx >> 6, c = idx & 63;
    WxPad[idx] = (c < 44) ? Wx[k * 44 + c] : 0.f;
}

// ---------------------------------------------------------------------------
// post_proj: one wave per row.
//   Cs[row][n]  = xdbl[row][28+n] + prompt_row @ Wp        (n = 0..15)
//   delta[row][d] = softplus(dtr @ Wdt + b_dt)              (dtr = xdbl[row][0..11])
// ---------------------------------------------------------------------------
__global__ __launch_bounds__(256) void post_proj(
    const float* __restrict__ xdbl, const float* __restrict__ prompt,
    const float* __restrict__ Wdt, const float* __restrict__ b_dt,
    const float* __restrict__ Wp,
    float* __restrict__ delta, float* __restrict__ Csv)
{
    const int wid = threadIdx.x >> 6, lane = threadIdx.x & 63;
    const int row = blockIdx.x * 4 + wid;

    // dtr (wave-uniform float4 loads)
    const float4* dp = (const float4*)&xdbl[(size_t)row * XDS];
    const float4 d0 = dp[0], d1 = dp[1], d2 = dp[2];
    const float dtr[RK] = {d0.x, d0.y, d0.z, d0.w, d1.x, d1.y, d1.z, d1.w,
                           d2.x, d2.y, d2.z, d2.w};

    // prompt @ Wp: lane = g*16+n; each g covers 48 of the 192 c's
    const int n16 = lane & 15, g = lane >> 4;
    const float* prow = prompt + (size_t)row * DM + g * 48;
    float pw = 0.f;
    #pragma unroll
    for (int cc = 0; cc < 48; cc += 4) {
        const float4 p4 = *(const float4*)&prow[cc];
        const int c = g * 48 + cc;
        pw += p4.x * Wp[(c    ) * NS + n16];
        pw += p4.y * Wp[(c + 1) * NS + n16];
        pw += p4.z * Wp[(c + 2) * NS + n16];
        pw += p4.w * Wp[(c + 3) * NS + n16];
    }
    pw += __shfl_xor(pw, 16);
    pw += __shfl_xor(pw, 32);
    if (lane < 16)
        Csv[(size_t)row * NS + lane] = xdbl[(size_t)row * XDS + 28 + lane] + pw;

    // delta: each lane computes 6 channels
    #pragma unroll
    for (int jj = 0; jj < 6; ++jj) {
        int dch = jj * 64 + lane;
        float acc = b_dt[dch];
        #pragma unroll
        for (int r = 0; r < RK; ++r) acc += dtr[r] * Wdt[r * DI + dch];
        delta[(size_t)row * DI + dch] = (acc > 20.f) ? acc : log1pf(__expf(acc));
    }
}

// ---------------------------------------------------------------------------
// Scan phase 1: per-chunk local scan from h=0 -> (prod a, h_out)
// Bs read from xdbl (cols 12..27, stride XDS).
// ---------------------------------------------------------------------------
__global__ __launch_bounds__(256) void scan_p1(
    const float* __restrict__ delta, const float* __restrict__ u,
    const float* __restrict__ xdbl, const float* __restrict__ A_log,
    float* __restrict__ Aprod, float* __restrict__ Hout)
{
    int bid = blockIdx.x;
    int dg = bid % (DI / 16);
    int c  = (bid / (DI / 16)) % NC;
    int b  = bid / ((DI / 16) * NC);
    int tid = threadIdx.x;
    int dl = tid >> 4, n = tid & 15;
    int d = dg * 16 + dl;
    float Adn = -__expf(A_log[d * NS + n]);
    float h = 0.f, ap = 1.f;
    int lbase = c * CH;
    for (int i = 0; i < CH; ++i) {
        int l = lbase + i;
        size_t off = ((size_t)(b * LL + l)) * DI + d;
        float dlt = delta[off];
        float uu  = u[off];
        float bs  = xdbl[(size_t)(b * LL + l) * XDS + 12 + n];
        float a = __expf(dlt * Adn);
        h = a * h + (dlt * uu) * bs;
        ap *= a;
    }
    size_t idx = (((size_t)(b * NC + c)) * DI + d) * NS + n;
    Aprod[idx] = ap;
    Hout[idx]  = h;
}

// ---------------------------------------------------------------------------
// Scan phase 2: sequential over chunks per (b,d,n) chain.  24576 threads.
// Writes chunk-entry state IN-PLACE over Aprod (read-before-write per thread).
// ---------------------------------------------------------------------------
__global__ __launch_bounds__(256) void scan_p2(
    float* __restrict__ Aprod, const float* __restrict__ Hout)
{
    int gid = blockIdx.x * 256 + threadIdx.x;   // (b*DI + d)*NS + n
    int n = gid & 15;
    int d = (gid >> 4) % DI;
    int b = gid / (DI * NS);
    float hin = 0.f;
    for (int c = 0; c < NC; ++c) {
        size_t idx = (((size_t)(b * NC + c)) * DI + d) * NS + n;
        float ap = Aprod[idx];
        float ho = Hout[idx];
        Aprod[idx] = hin;          // becomes Hin
        hin = ap * hin + ho;
    }
}

// ---------------------------------------------------------------------------
// Scan phase 3: re-scan chunk from true h_in, emit y = h.C + u*D
// ---------------------------------------------------------------------------
__global__ __launch_bounds__(256) void scan_p3(
    const float* __restrict__ delta, const float* __restrict__ u,
    const float* __restrict__ xdbl, const float* __restrict__ Csv,
    const float* __restrict__ Hin, const float* __restrict__ A_log,
    const float* __restrict__ Dvec, float* __restrict__ y)
{
    int bid = blockIdx.x;
    int dg = bid % (DI / 16);
    int c  = (bid / (DI / 16)) % NC;
    int b  = bid / ((DI / 16) * NC);
    int tid = threadIdx.x;
    int dl = tid >> 4, n = tid & 15;
    int d = dg * 16 + dl;
    float Adn = -__expf(A_log[d * NS + n]);
    float Dd = Dvec[d];
    float h = Hin[(((size_t)(b * NC + c)) * DI + d) * NS + n];
    int lbase = c * CH;
    for (int i = 0; i < CH; ++i) {
        int l = lbase + i;
        size_t off = ((size_t)(b * LL + l)) * DI + d;
        float dlt = delta[off];
        float uu  = u[off];
        float bs = xdbl[(size_t)(b * LL + l) * XDS + 12 + n];
        float cs = Csv[(size_t)(b * LL + l) * NS + n];
        float a = __expf(dlt * Adn);
        h = a * h + (dlt * uu) * bs;
        float p = h * cs;
        p += __shfl_xor(p, 1);
        p += __shfl_xor(p, 2);
        p += __shfl_xor(p, 4);
        p += __shfl_xor(p, 8);
        if (n == 0) y[off] = p + uu * Dd;
    }
}

// ---------------------------------------------------------------------------
// LayerNorm over d (384) + SiLU(z) gating.  One wave per row.
// ---------------------------------------------------------------------------
__global__ __launch_bounds__(256) void ln_gate(
    const float* __restrict__ y, const float* __restrict__ z,
    const float* __restrict__ ln_g, const float* __restrict__ ln_b,
    float* __restrict__ yin)
{
    int wid = threadIdx.x >> 6, lane = threadIdx.x & 63;
    int row = blockIdx.x * 4 + wid;
    float v[6];
    float s = 0.f, sq = 0.f;
    #pragma unroll
    for (int i = 0; i < 6; ++i) {
        v[i] = y[(size_t)row * DI + i * 64 + lane];
        s += v[i];
        sq += v[i] * v[i];
    }
    #pragma unroll
    for (int m = 1; m < 64; m <<= 1) {
        s  += __shfl_xor(s, m);
        sq += __shfl_xor(sq, m);
    }
    float mu = s * (1.f / DI);
    float var = sq * (1.f / DI) - mu * mu;
    float inv = rsqrtf(var + 1e-5f);
    #pragma unroll
    for (int i = 0; i < 6; ++i) {
        int dch = i * 64 + lane;
        float yn = (v[i] - mu) * inv * ln_g[dch] + ln_b[dch];
        float zz = z[(size_t)row * DI + dch];
        yin[(size_t)row * DI + dch] = yn * fsilu(zz);
    }
}

// ---------------------------------------------------------------------------
extern "C" void kernel_launch(void* const* d_in, const int* in_sizes, int n_in,
                              void* d_out, int out_size, void* d_ws, size_t ws_size,
                              hipStream_t stream)
{
    const float* x      = (const float*)d_in[0];
    const float* prompt = (const float*)d_in[1];
    const float* W_in   = (const float*)d_in[2];
    const float* conv_w = (const float*)d_in[3];
    const float* conv_b = (const float*)d_in[4];
    const float* Wx     = (const float*)d_in[5];
    const float* Wdt    = (const float*)d_in[6];
    const float* b_dt   = (const float*)d_in[7];
    const float* A_log  = (const float*)d_in[8];
    const float* Dvec   = (const float*)d_in[9];
    const float* Wp     = (const float*)d_in[10];
    const float* ln_g   = (const float*)d_in[11];
    const float* ln_b   = (const float*)d_in[12];
    const float* Wout   = (const float*)d_in[13];
    float* out = (float*)d_out;

    char* ws = (char*)d_ws;
    const size_t SZ_BLD = (size_t)ROWS * DI * 4;   // 25165824 B
    float* xi    = (float*)(ws);
    float* z     = (float*)(ws + SZ_BLD);
    float* u     = (float*)(ws + 2 * SZ_BLD);
    float* delta = (float*)(ws + 3 * SZ_BLD);
    float* y     = (float*)(ws + 4 * SZ_BLD);
    char*  p     = ws + 5 * SZ_BLD;
    float* xdbl  = (float*)p;            p += (size_t)ROWS * XDS * 4;         // 4 MB
    float* Csv   = (float*)p;            p += (size_t)ROWS * NS * 4;          // 1 MB
    float* Aprod = (float*)p;            p += (size_t)BB * NC * DI * NS * 4;  // 6.29 MB
    float* Hout  = (float*)p;            p += (size_t)BB * NC * DI * NS * 4;
    float* WxPad = (float*)p;            p += (size_t)DI * XDS * 4;           // 98 KB
    float* yin   = xi;   // xi dead after conv

    // 0. WxPad (independent, tiny)
    build_wxpad<<<(DI * XDS) / 256, 256, 0, stream>>>(Wx, WxPad);
    // 1. xz = x @ W_in, split -> xi, z
    {
        dim3 g(ROWS / 64, 768 / 64);
        gemm_f32_64x64<true><<<g, 256, 0, stream>>>(x, W_in, xi, z, ROWS, 768, DM, DI);
    }
    // 2. depthwise conv + bias + SiLU -> u
    conv_dw_silu<<<(BB * HH * WW * 96) / 256, 256, 0, stream>>>(xi, conv_w, conv_b, u);
    // 3a. xdbl = u @ WxPad  (16384 x 64, K=384)
    {
        dim3 g(ROWS / 64, 1);
        gemm_f32_64x64<false><<<g, 256, 0, stream>>>(u, WxPad, xdbl, nullptr, ROWS, XDS, DI, 0);
    }
    // 3b. Cs (+prompt@Wp) and delta (softplus low-rank)
    post_proj<<<ROWS / 4, 256, 0, stream>>>(xdbl, prompt, Wdt, b_dt, Wp, delta, Csv);
    // 4-6. chunked selective scan (p2 writes Hin in-place over Aprod)
    scan_p1<<<BB * NC * (DI / 16), 256, 0, stream>>>(delta, u, xdbl, A_log, Aprod, Hout);
    scan_p2<<<(BB * DI * NS) / 256, 256, 0, stream>>>(Aprod, Hout);
    scan_p3<<<BB * NC * (DI / 16), 256, 0, stream>>>(delta, u, xdbl, Csv, Aprod, A_log, Dvec, y);
    // 7. LayerNorm + SiLU(z) gate -> yin (reuses xi)
    ln_gate<<<ROWS / 4, 256, 0, stream>>>(y, z, ln_g, ln_b, yin);
    // 8. out = yin @ Wout
    {
        dim3 g(ROWS / 64, DM / 64);
        gemm_f32_64x64<false><<<g, 256, 0, stream>>>(yin, Wout, out, nullptr, ROWS, DM, DI, 0);
    }
}

// Round 4
// 434.006 us; speedup vs baseline: 1.2247x; 1.0331x over previous
//
#include <hip/hip_runtime.h>
#include <hip/hip_bf16.h>

// Problem constants
#define BB 4
#define HH 64
#define WW 64
#define LL 4096           // HH*WW
#define DM 192            // D_MODEL
#define DI 384            // D_INNER
#define NS 16             // D_STATE
#define RK 12             // DT_RANK
#define NC 128            // number of scan chunks
#define CH 32             // chunk length (NC*CH == LL)
#define ROWS 16384        // BB*LL
#define XDS 64            // xdbl row stride (44 cols padded to 64)

__device__ __forceinline__ float fsilu(float x) {
    return x / (1.0f + __expf(-x));
}

// ---------------------------------------------------------------------------
// Generic 64x64 tiled f32 GEMM, 256 threads, 4x4 micro-tile.
// SPLIT=true: N=2*halfN, writes col<halfN to C0, col>=halfN to C1 (both halfN-wide).
// ---------------------------------------------------------------------------
template<bool SPLIT>
__global__ __launch_bounds__(256) void gemm_f32_64x64(
    const float* __restrict__ A, const float* __restrict__ B,
    float* __restrict__ C0, float* __restrict__ C1,
    int M, int N, int K, int halfN)
{
    __shared__ float As[16][65];   // padded: avoid 16-way write conflict
    __shared__ float Bs[16][64];
    const int tid = threadIdx.x;
    const int tx = tid & 15, ty = tid >> 4;
    const int row0 = blockIdx.x * 64, col0 = blockIdx.y * 64;
    float acc[4][4] = {};
    for (int k0 = 0; k0 < K; k0 += 16) {
        #pragma unroll
        for (int i = 0; i < 4; ++i) {
            int e = tid + 256 * i;
            int r = e >> 4, kk = e & 15;
            As[kk][r] = A[(row0 + r) * K + k0 + kk];
        }
        #pragma unroll
        for (int i = 0; i < 4; ++i) {
            int e = tid + 256 * i;
            int r = e >> 6, c = e & 63;
            Bs[r][c] = B[(k0 + r) * N + col0 + c];
        }
        __syncthreads();
        #pragma unroll
        for (int kk = 0; kk < 16; ++kk) {
            float a[4], bb[4];
            #pragma unroll
            for (int i = 0; i < 4; ++i) a[i] = As[kk][ty * 4 + i];
            #pragma unroll
            for (int j = 0; j < 4; ++j) bb[j] = Bs[kk][tx * 4 + j];
            #pragma unroll
            for (int i = 0; i < 4; ++i)
                #pragma unroll
                for (int j = 0; j < 4; ++j)
                    acc[i][j] += a[i] * bb[j];
        }
        __syncthreads();
    }
    #pragma unroll
    for (int i = 0; i < 4; ++i) {
        int row = row0 + ty * 4 + i;
        int col = col0 + tx * 4;
        float4 v = make_float4(acc[i][0], acc[i][1], acc[i][2], acc[i][3]);
        if (SPLIT) {
            if (col < halfN) *(float4*)&C0[(size_t)row * halfN + col] = v;
            else             *(float4*)&C1[(size_t)row * halfN + col - halfN] = v;
        } else {
            *(float4*)&C0[(size_t)row * N + col] = v;
        }
    }
}

// ---------------------------------------------------------------------------
// Depthwise 3x3 conv (channel-last), bias + SiLU.  xi: (B,H,W,DI) -> u: (B,L,DI)
// ---------------------------------------------------------------------------
__global__ __launch_bounds__(256) void conv_dw_silu(
    const float* __restrict__ xi, const float* __restrict__ conv_w,
    const float* __restrict__ conv_b, float* __restrict__ u)
{
    int idx = blockIdx.x * 256 + threadIdx.x;   // total BB*HH*WW*96
    int c4 = idx % 96;
    int rest = idx / 96;
    int w = rest % WW; rest /= WW;
    int h = rest % HH;
    int b = rest / HH;
    int c = c4 * 4;

    float wgt[4][9];
    #pragma unroll
    for (int q = 0; q < 4; ++q)
        #pragma unroll
        for (int t = 0; t < 9; ++t)
            wgt[q][t] = conv_w[(c + q) * 9 + t];

    float4 acc = *(const float4*)&conv_b[c];
    #pragma unroll
    for (int kh = 0; kh < 3; ++kh) {
        int hh = h + kh - 1;
        if ((unsigned)hh >= HH) continue;
        #pragma unroll
        for (int kw = 0; kw < 3; ++kw) {
            int ww = w + kw - 1;
            if ((unsigned)ww >= WW) continue;
            const float4 xv = *(const float4*)&xi[(((size_t)(b * HH + hh)) * WW + ww) * DI + c];
            int t = kh * 3 + kw;
            acc.x += xv.x * wgt[0][t];
            acc.y += xv.y * wgt[1][t];
            acc.z += xv.z * wgt[2][t];
            acc.w += xv.w * wgt[3][t];
        }
    }
    acc.x = fsilu(acc.x); acc.y = fsilu(acc.y);
    acc.z = fsilu(acc.z); acc.w = fsilu(acc.w);
    *(float4*)&u[(((size_t)b * LL) + h * WW + w) * DI + c] = acc;
}

// ---------------------------------------------------------------------------
// WxPad: (384 x 44) -> (384 x 64), cols 44..63 = 0
// ---------------------------------------------------------------------------
__global__ __launch_bounds__(256) void build_wxpad(
    const float* __restrict__ Wx, float* __restrict__ WxPad)
{
    int idx = blockIdx.x * 256 + threadIdx.x;   // 384*64
    int k = idx >> 6, c = idx & 63;
    WxPad[idx] = (c < 44) ? Wx[k * 44 + c] : 0.f;
}

// ---------------------------------------------------------------------------
// post_proj: one wave per row.
//   Cs[row][n]  = xdbl[row][28+n] + prompt_row @ Wp        (n = 0..15)
//   delta[row][d] = softplus(dtr @ Wdt + b_dt)              (dtr = xdbl[row][0..11])
// ---------------------------------------------------------------------------
__global__ __launch_bounds__(256) void post_proj(
    const float* __restrict__ xdbl, const float* __restrict__ prompt,
    const float* __restrict__ Wdt, const float* __restrict__ b_dt,
    const float* __restrict__ Wp,
    float* __restrict__ delta, float* __restrict__ Csv)
{
    const int wid = threadIdx.x >> 6, lane = threadIdx.x & 63;
    const int row = blockIdx.x * 4 + wid;

    // dtr (wave-uniform float4 loads)
    const float4* dp = (const float4*)&xdbl[(size_t)row * XDS];
    const float4 d0 = dp[0], d1 = dp[1], d2 = dp[2];
    const float dtr[RK] = {d0.x, d0.y, d0.z, d0.w, d1.x, d1.y, d1.z, d1.w,
                           d2.x, d2.y, d2.z, d2.w};

    // prompt @ Wp: lane = g*16+n; each g covers 48 of the 192 c's
    const int n16 = lane & 15, g = lane >> 4;
    const float* prow = prompt + (size_t)row * DM + g * 48;
    float pw = 0.f;
    #pragma unroll
    for (int cc = 0; cc < 48; cc += 4) {
        const float4 p4 = *(const float4*)&prow[cc];
        const int c = g * 48 + cc;
        pw += p4.x * Wp[(c    ) * NS + n16];
        pw += p4.y * Wp[(c + 1) * NS + n16];
        pw += p4.z * Wp[(c + 2) * NS + n16];
        pw += p4.w * Wp[(c + 3) * NS + n16];
    }
    pw += __shfl_xor(pw, 16);
    pw += __shfl_xor(pw, 32);
    if (lane < 16)
        Csv[(size_t)row * NS + lane] = xdbl[(size_t)row * XDS + 28 + lane] + pw;

    // delta: each lane computes 6 channels
    #pragma unroll
    for (int jj = 0; jj < 6; ++jj) {
        int dch = jj * 64 + lane;
        float acc = b_dt[dch];
        #pragma unroll
        for (int r = 0; r < RK; ++r) acc += dtr[r] * Wdt[r * DI + dch];
        delta[(size_t)row * DI + dch] = (acc > 20.f) ? acc : log1pf(__expf(acc));
    }
}

// ---------------------------------------------------------------------------
// Scan phase 1 v2: one thread per (b,chunk,d); all 16 n-states in registers.
// delta/u loads lane-coalesced over d; Bs loads wave-uniform.
// Writes Aprod/Hout at idx = ((b*NC+c)*DI + d)*NS + n.
// ---------------------------------------------------------------------------
__global__ __launch_bounds__(256) void scan_p1_v2(
    const float* __restrict__ delta, const float* __restrict__ u,
    const float* __restrict__ xdbl, const float* __restrict__ A_log,
    float* __restrict__ Aprod, float* __restrict__ Hout)
{
    const int g = blockIdx.x * 256 + threadIdx.x;   // bc*DI + d
    const int d = g % DI;
    const int bc = g / DI;                           // b*NC + c
    const int b = bc / NC, c = bc % NC;

    float Adn[NS], h[NS], ap[NS];
    #pragma unroll
    for (int n = 0; n < NS; ++n) {
        Adn[n] = -__expf(A_log[d * NS + n]);
        h[n] = 0.f;
        ap[n] = 1.f;
    }
    const int lbase = c * CH;
    for (int i = 0; i < CH; ++i) {
        const size_t roff = (size_t)(b * LL + lbase + i);
        const float dlt = delta[roff * DI + d];
        const float uu  = u[roff * DI + d];
        const float du  = dlt * uu;
        const float* rowx = xdbl + roff * XDS + 12;   // Bs cols 12..27
        #pragma unroll
        for (int q = 0; q < 4; ++q) {
            const float4 bv = *(const float4*)(rowx + q * 4);
            const float bs[4] = {bv.x, bv.y, bv.z, bv.w};
            #pragma unroll
            for (int j = 0; j < 4; ++j) {
                const int n = q * 4 + j;
                const float a = __expf(dlt * Adn[n]);
                h[n] = a * h[n] + du * bs[j];
                ap[n] *= a;
            }
        }
    }
    const size_t idx = ((size_t)bc * DI + d) * NS;
    #pragma unroll
    for (int q = 0; q < 4; ++q) {
        *(float4*)&Aprod[idx + q * 4] =
            make_float4(ap[q*4], ap[q*4+1], ap[q*4+2], ap[q*4+3]);
        *(float4*)&Hout[idx + q * 4] =
            make_float4(h[q*4], h[q*4+1], h[q*4+2], h[q*4+3]);
    }
}

// ---------------------------------------------------------------------------
// Scan phase 2: sequential over chunks per (b,d,n) chain.  24576 threads.
// Writes chunk-entry state IN-PLACE over Aprod (read-before-write per thread).
// ---------------------------------------------------------------------------
__global__ __launch_bounds__(256) void scan_p2(
    float* __restrict__ Aprod, const float* __restrict__ Hout)
{
    int gid = blockIdx.x * 256 + threadIdx.x;   // (b*DI + d)*NS + n
    int n = gid & 15;
    int d = (gid >> 4) % DI;
    int b = gid / (DI * NS);
    float hin = 0.f;
    for (int c = 0; c < NC; ++c) {
        size_t idx = (((size_t)(b * NC + c)) * DI + d) * NS + n;
        float ap = Aprod[idx];
        float ho = Hout[idx];
        Aprod[idx] = hin;          // becomes Hin
        hin = ap * hin + ho;
    }
}

// ---------------------------------------------------------------------------
// Scan phase 3 + LayerNorm + SiLU(z) gate, fused.
// Block = 384 threads = one (b,chunk), thread d owns 16 n-states in registers.
// Per step: y_d = sum_n h[n]*cs[n] + u*D; block-reduce mean/var over d=384;
// write gated yin directly.  (y buffer eliminated.)
// ---------------------------------------------------------------------------
__global__ __launch_bounds__(384) void scan_p3_ln(
    const float* __restrict__ delta, const float* __restrict__ u,
    const float* __restrict__ xdbl, const float* __restrict__ Csv,
    const float* __restrict__ Hin, const float* __restrict__ A_log,
    const float* __restrict__ Dvec, const float* __restrict__ z,
    const float* __restrict__ ln_g, const float* __restrict__ ln_b,
    float* __restrict__ yin)
{
    __shared__ float red_s[2][8], red_sq[2][8];
    const int d = threadIdx.x;                 // 0..383
    const int bc = blockIdx.x;                 // b*NC + c
    const int b = bc / NC, c = bc % NC;
    const int wid = d >> 6, lane = d & 63;

    float Adn[NS], h[NS];
    #pragma unroll
    for (int n = 0; n < NS; ++n)
        Adn[n] = -__expf(A_log[d * NS + n]);
    {
        const size_t idx = ((size_t)bc * DI + d) * NS;
        #pragma unroll
        for (int q = 0; q < 4; ++q) {
            const float4 hv = *(const float4*)&Hin[idx + q * 4];
            h[q*4] = hv.x; h[q*4+1] = hv.y; h[q*4+2] = hv.z; h[q*4+3] = hv.w;
        }
    }
    const float Dd = Dvec[d];
    const float lg = ln_g[d], lb = ln_b[d];

    const int lbase = c * CH;
    for (int i = 0; i < CH; ++i) {
        const size_t roff = (size_t)(b * LL + lbase + i);
        const float dlt = delta[roff * DI + d];
        const float uu  = u[roff * DI + d];
        const float du  = dlt * uu;
        const float* rowx = xdbl + roff * XDS + 12;   // Bs cols 12..27
        const float* rowc = Csv + roff * NS;
        float acc = uu * Dd;
        #pragma unroll
        for (int q = 0; q < 4; ++q) {
            const float4 bv = *(const float4*)(rowx + q * 4);
            const float4 cv = *(const float4*)(rowc + q * 4);
            const float bs[4] = {bv.x, bv.y, bv.z, bv.w};
            const float cs[4] = {cv.x, cv.y, cv.z, cv.w};
            #pragma unroll
            for (int j = 0; j < 4; ++j) {
                const int n = q * 4 + j;
                const float a = __expf(dlt * Adn[n]);
                h[n] = a * h[n] + du * bs[j];
                acc += h[n] * cs[j];
            }
        }
        // block LayerNorm reduce over 384 d's (parity LDS double-buffer)
        float s = acc, sq = acc * acc;
        #pragma unroll
        for (int m = 1; m < 64; m <<= 1) {
            s  += __shfl_xor(s, m);
            sq += __shfl_xor(sq, m);
        }
        const int par = i & 1;
        if (lane == 0) { red_s[par][wid] = s; red_sq[par][wid] = sq; }
        __syncthreads();
        s = red_s[par][0] + red_s[par][1] + red_s[par][2]
          + red_s[par][3] + red_s[par][4] + red_s[par][5];
        sq = red_sq[par][0] + red_sq[par][1] + red_sq[par][2]
           + red_sq[par][3] + red_sq[par][4] + red_sq[par][5];
        const float mu = s * (1.f / DI);
        const float var = sq * (1.f / DI) - mu * mu;
        const float inv = rsqrtf(var + 1e-5f);
        const float yn = (acc - mu) * inv * lg + lb;
        const float zz = z[roff * DI + d];
        yin[roff * DI + d] = yn * fsilu(zz);
    }
}

// ---------------------------------------------------------------------------
extern "C" void kernel_launch(void* const* d_in, const int* in_sizes, int n_in,
                              void* d_out, int out_size, void* d_ws, size_t ws_size,
                              hipStream_t stream)
{
    const float* x      = (const float*)d_in[0];
    const float* prompt = (const float*)d_in[1];
    const float* W_in   = (const float*)d_in[2];
    const float* conv_w = (const float*)d_in[3];
    const float* conv_b = (const float*)d_in[4];
    const float* Wx     = (const float*)d_in[5];
    const float* Wdt    = (const float*)d_in[6];
    const float* b_dt   = (const float*)d_in[7];
    const float* A_log  = (const float*)d_in[8];
    const float* Dvec   = (const float*)d_in[9];
    const float* Wp     = (const float*)d_in[10];
    const float* ln_g   = (const float*)d_in[11];
    const float* ln_b   = (const float*)d_in[12];
    const float* Wout   = (const float*)d_in[13];
    float* out = (float*)d_out;

    char* ws = (char*)d_ws;
    const size_t SZ_BLD = (size_t)ROWS * DI * 4;   // 25165824 B
    float* xi    = (float*)(ws);
    float* z     = (float*)(ws + SZ_BLD);
    float* u     = (float*)(ws + 2 * SZ_BLD);
    float* delta = (float*)(ws + 3 * SZ_BLD);
    char*  p     = ws + 4 * SZ_BLD;
    float* xdbl  = (float*)p;            p += (size_t)ROWS * XDS * 4;         // 4 MB
    float* Csv   = (float*)p;            p += (size_t)ROWS * NS * 4;          // 1 MB
    float* Aprod = (float*)p;            p += (size_t)BB * NC * DI * NS * 4;  // 12.58 MB
    float* Hout  = (float*)p;            p += (size_t)BB * NC * DI * NS * 4;  // 12.58 MB
    float* WxPad = (float*)p;            p += (size_t)DI * XDS * 4;           // 98 KB
    float* yin   = xi;   // xi dead after conv

    // 0. WxPad (independent, tiny)
    build_wxpad<<<(DI * XDS) / 256, 256, 0, stream>>>(Wx, WxPad);
    // 1. xz = x @ W_in, split -> xi, z
    {
        dim3 g(ROWS / 64, 768 / 64);
        gemm_f32_64x64<true><<<g, 256, 0, stream>>>(x, W_in, xi, z, ROWS, 768, DM, DI);
    }
    // 2. depthwise conv + bias + SiLU -> u
    conv_dw_silu<<<(BB * HH * WW * 96) / 256, 256, 0, stream>>>(xi, conv_w, conv_b, u);
    // 3a. xdbl = u @ WxPad  (16384 x 64, K=384)
    {
        dim3 g(ROWS / 64, 1);
        gemm_f32_64x64<false><<<g, 256, 0, stream>>>(u, WxPad, xdbl, nullptr, ROWS, XDS, DI, 0);
    }
    // 3b. Cs (+prompt@Wp) and delta (softplus low-rank)
    post_proj<<<ROWS / 4, 256, 0, stream>>>(xdbl, prompt, Wdt, b_dt, Wp, delta, Csv);
    // 4-6. chunked selective scan (p2 writes Hin in-place over Aprod)
    scan_p1_v2<<<(BB * NC * DI) / 256, 256, 0, stream>>>(delta, u, xdbl, A_log, Aprod, Hout);
    scan_p2<<<(BB * DI * NS) / 256, 256, 0, stream>>>(Aprod, Hout);
    // 7. scan replay + LayerNorm + SiLU(z) gate -> yin (reuses xi)
    scan_p3_ln<<<BB * NC, 384, 0, stream>>>(delta, u, xdbl, Csv, Aprod, A_log,
                                            Dvec, z, ln_g, ln_b, yin);
    // 8. out = yin @ Wout
    {
        dim3 g(ROWS / 64, DM / 64);
        gemm_f32_64x64<false><<<g, 256, 0, stream>>>(yin, Wout, out, nullptr, ROWS, DM, DI, 0);
    }
}

// Round 5
// 330.878 us; speedup vs baseline: 1.6064x; 1.3117x over previous
//
#include <hip/hip_runtime.h>
#include <hip/hip_bf16.h>

// Problem constants
#define BB 4
#define HH 64
#define WW 64
#define LL 4096           // HH*WW
#define DM 192            // D_MODEL
#define DI 384            // D_INNER
#define NS 16             // D_STATE
#define RK 12             // DT_RANK
#define NC 128            // number of scan chunks
#define CH 32             // chunk length (NC*CH == LL)
#define ROWS 16384        // BB*LL
#define XDS 64            // xdbl row stride (44 cols padded to 64)

typedef __bf16 bf16x8 __attribute__((ext_vector_type(8)));
typedef float  f32x4  __attribute__((ext_vector_type(4)));

__device__ __forceinline__ float fsilu(float x) {
    return x / (1.0f + __expf(-x));
}

// f32 -> bf16 (RNE)
__device__ __forceinline__ unsigned short f2bf(float f) {
    unsigned int u = __float_as_uint(f);
    unsigned int r = (u + 0x7fffu + ((u >> 16) & 1u)) >> 16;
    return (unsigned short)r;
}

// ---------------------------------------------------------------------------
// Vectorized f32 -> bf16 convert (n multiple of 4)
// ---------------------------------------------------------------------------
__global__ __launch_bounds__(256) void f32_to_bf16_vec(
    const float* __restrict__ src, unsigned short* __restrict__ dst, int n4)
{
    int i = blockIdx.x * 256 + threadIdx.x;
    if (i < n4) {
        float4 v = ((const float4*)src)[i];
        ((ushort4*)dst)[i] = make_ushort4(f2bf(v.x), f2bf(v.y), f2bf(v.z), f2bf(v.w));
    }
}

// ---------------------------------------------------------------------------
// Build transposed bf16 weight: src (K x Nsrc f32) -> dst (Nrows x K bf16),
// rows n >= Nsrc are zero (padding).
// ---------------------------------------------------------------------------
__global__ __launch_bounds__(256) void build_bt(
    const float* __restrict__ src, unsigned short* __restrict__ dst,
    int K, int Nsrc, int Nrows)
{
    int idx = blockIdx.x * 256 + threadIdx.x;
    if (idx >= Nrows * K) return;
    int n = idx / K, k = idx % K;
    dst[idx] = (n < Nsrc) ? f2bf(src[k * Nsrc + n]) : (unsigned short)0;
}

// ---------------------------------------------------------------------------
// bf16 MFMA GEMM: C(MxN f32) = A(MxK bf16) * BT^T (BT is N x K bf16).
// 64x64 tile, BK=32. 256 thr = 4 waves (2x2), each wave 32x32 via 2x2
// mfma_f32_16x16x32_bf16 fragments. LDS row stride 80B (2-way bank alias).
// SPLIT: halfN-wide C0/C1, block column fully inside one half (col0 % 64 == 0).
// ---------------------------------------------------------------------------
template<bool SPLIT>
__global__ __launch_bounds__(256) void gemm_bf16_mfma(
    const unsigned short* __restrict__ A, const unsigned short* __restrict__ BT,
    float* __restrict__ C0, float* __restrict__ C1,
    int M, int N, int K, int halfN)
{
    __shared__ __align__(16) char lds[64 * 80 * 2];
    char* As = lds;
    char* Bs = lds + 64 * 80;
    const int tid = threadIdx.x;
    const int w = tid >> 6, lane = tid & 63;
    const int wm = w >> 1, wn = w & 1;
    const int row0 = blockIdx.x * 64, col0 = blockIdx.y * 64;
    const int r = tid >> 2, cch = tid & 3;
    const int l15 = lane & 15, k8 = lane >> 4;

    f32x4 acc[2][2] = {};
    for (int k0 = 0; k0 < K; k0 += 32) {
        *(float4*)(As + r * 80 + cch * 16) =
            *(const float4*)(A + (size_t)(row0 + r) * K + k0 + cch * 8);
        *(float4*)(Bs + r * 80 + cch * 16) =
            *(const float4*)(BT + (size_t)(col0 + r) * K + k0 + cch * 8);
        __syncthreads();
        bf16x8 a0 = *(const bf16x8*)(As + (wm * 32 +      l15) * 80 + k8 * 16);
        bf16x8 a1 = *(const bf16x8*)(As + (wm * 32 + 16 + l15) * 80 + k8 * 16);
        bf16x8 b0 = *(const bf16x8*)(Bs + (wn * 32 +      l15) * 80 + k8 * 16);
        bf16x8 b1 = *(const bf16x8*)(Bs + (wn * 32 + 16 + l15) * 80 + k8 * 16);
        acc[0][0] = __builtin_amdgcn_mfma_f32_16x16x32_bf16(a0, b0, acc[0][0], 0, 0, 0);
        acc[0][1] = __builtin_amdgcn_mfma_f32_16x16x32_bf16(a0, b1, acc[0][1], 0, 0, 0);
        acc[1][0] = __builtin_amdgcn_mfma_f32_16x16x32_bf16(a1, b0, acc[1][0], 0, 0, 0);
        acc[1][1] = __builtin_amdgcn_mfma_f32_16x16x32_bf16(a1, b1, acc[1][1], 0, 0, 0);
        __syncthreads();
    }

    // epilogue: C/D layout col = lane&15, row = (lane>>4)*4 + reg
    float* Cw;
    int cbase, cstride;
    if (SPLIT) {
        cstride = halfN;
        if (col0 < halfN) { Cw = C0; cbase = col0; }
        else              { Cw = C1; cbase = col0 - halfN; }
    } else {
        Cw = C0; cbase = col0; cstride = N;
    }
    #pragma unroll
    for (int fm = 0; fm < 2; ++fm)
        #pragma unroll
        for (int fn = 0; fn < 2; ++fn)
            #pragma unroll
            for (int reg = 0; reg < 4; ++reg) {
                int row = row0 + wm * 32 + fm * 16 + k8 * 4 + reg;
                int col = cbase + wn * 32 + fn * 16 + l15;
                Cw[(size_t)row * cstride + col] = acc[fm][fn][reg];
            }
}

// ---------------------------------------------------------------------------
// Depthwise 3x3 conv (channel-last), bias + SiLU.  xi: (B,H,W,DI) -> u (f32)
// and u_bf (bf16, for the xdbl MFMA GEMM).
// ---------------------------------------------------------------------------
__global__ __launch_bounds__(256) void conv_dw_silu(
    const float* __restrict__ xi, const float* __restrict__ conv_w,
    const float* __restrict__ conv_b, float* __restrict__ u,
    unsigned short* __restrict__ u_bf)
{
    int idx = blockIdx.x * 256 + threadIdx.x;   // total BB*HH*WW*96
    int c4 = idx % 96;
    int rest = idx / 96;
    int w = rest % WW; rest /= WW;
    int h = rest % HH;
    int b = rest / HH;
    int c = c4 * 4;

    float wgt[4][9];
    #pragma unroll
    for (int q = 0; q < 4; ++q)
        #pragma unroll
        for (int t = 0; t < 9; ++t)
            wgt[q][t] = conv_w[(c + q) * 9 + t];

    float4 acc = *(const float4*)&conv_b[c];
    #pragma unroll
    for (int kh = 0; kh < 3; ++kh) {
        int hh = h + kh - 1;
        if ((unsigned)hh >= HH) continue;
        #pragma unroll
        for (int kw = 0; kw < 3; ++kw) {
            int ww = w + kw - 1;
            if ((unsigned)ww >= WW) continue;
            const float4 xv = *(const float4*)&xi[(((size_t)(b * HH + hh)) * WW + ww) * DI + c];
            int t = kh * 3 + kw;
            acc.x += xv.x * wgt[0][t];
            acc.y += xv.y * wgt[1][t];
            acc.z += xv.z * wgt[2][t];
            acc.w += xv.w * wgt[3][t];
        }
    }
    acc.x = fsilu(acc.x); acc.y = fsilu(acc.y);
    acc.z = fsilu(acc.z); acc.w = fsilu(acc.w);
    size_t off = (((size_t)b * LL) + h * WW + w) * DI + c;
    *(float4*)&u[off] = acc;
    *(ushort4*)&u_bf[off] = make_ushort4(f2bf(acc.x), f2bf(acc.y), f2bf(acc.z), f2bf(acc.w));
}

// ---------------------------------------------------------------------------
// post_proj: one wave per row.
//   Cs[row][n]  = xdbl[row][28+n] + prompt_row @ Wp        (n = 0..15)
//   delta[row][d] = softplus(dtr @ Wdt + b_dt)              (dtr = xdbl[row][0..11])
// ---------------------------------------------------------------------------
__global__ __launch_bounds__(256) void post_proj(
    const float* __restrict__ xdbl, const float* __restrict__ prompt,
    const float* __restrict__ Wdt, const float* __restrict__ b_dt,
    const float* __restrict__ Wp,
    float* __restrict__ delta, float* __restrict__ Csv)
{
    const int wid = threadIdx.x >> 6, lane = threadIdx.x & 63;
    const int row = blockIdx.x * 4 + wid;

    // dtr (wave-uniform float4 loads)
    const float4* dp = (const float4*)&xdbl[(size_t)row * XDS];
    const float4 d0 = dp[0], d1 = dp[1], d2 = dp[2];
    const float dtr[RK] = {d0.x, d0.y, d0.z, d0.w, d1.x, d1.y, d1.z, d1.w,
                           d2.x, d2.y, d2.z, d2.w};

    // prompt @ Wp: lane = g*16+n; each g covers 48 of the 192 c's
    const int n16 = lane & 15, g = lane >> 4;
    const float* prow = prompt + (size_t)row * DM + g * 48;
    float pw = 0.f;
    #pragma unroll
    for (int cc = 0; cc < 48; cc += 4) {
        const float4 p4 = *(const float4*)&prow[cc];
        const int c = g * 48 + cc;
        pw += p4.x * Wp[(c    ) * NS + n16];
        pw += p4.y * Wp[(c + 1) * NS + n16];
        pw += p4.z * Wp[(c + 2) * NS + n16];
        pw += p4.w * Wp[(c + 3) * NS + n16];
    }
    pw += __shfl_xor(pw, 16);
    pw += __shfl_xor(pw, 32);
    if (lane < 16)
        Csv[(size_t)row * NS + lane] = xdbl[(size_t)row * XDS + 28 + lane] + pw;

    // delta: each lane computes 6 channels
    #pragma unroll
    for (int jj = 0; jj < 6; ++jj) {
        int dch = jj * 64 + lane;
        float acc = b_dt[dch];
        #pragma unroll
        for (int r = 0; r < RK; ++r) acc += dtr[r] * Wdt[r * DI + dch];
        delta[(size_t)row * DI + dch] = (acc > 20.f) ? acc : log1pf(__expf(acc));
    }
}

// ---------------------------------------------------------------------------
// Scan phase 1: one thread per (b,chunk,d); all 16 n-states in registers.
// ---------------------------------------------------------------------------
__global__ __launch_bounds__(256) void scan_p1_v2(
    const float* __restrict__ delta, const float* __restrict__ u,
    const float* __restrict__ xdbl, const float* __restrict__ A_log,
    float* __restrict__ Aprod, float* __restrict__ Hout)
{
    const int g = blockIdx.x * 256 + threadIdx.x;   // bc*DI + d
    const int d = g % DI;
    const int bc = g / DI;                           // b*NC + c
    const int b = bc / NC, c = bc % NC;

    float Adn[NS], h[NS], ap[NS];
    #pragma unroll
    for (int n = 0; n < NS; ++n) {
        Adn[n] = -__expf(A_log[d * NS + n]);
        h[n] = 0.f;
        ap[n] = 1.f;
    }
    const int lbase = c * CH;
    for (int i = 0; i < CH; ++i) {
        const size_t roff = (size_t)(b * LL + lbase + i);
        const float dlt = delta[roff * DI + d];
        const float uu  = u[roff * DI + d];
        const float du  = dlt * uu;
        const float* rowx = xdbl + roff * XDS + 12;   // Bs cols 12..27
        #pragma unroll
        for (int q = 0; q < 4; ++q) {
            const float4 bv = *(const float4*)(rowx + q * 4);
            const float bs[4] = {bv.x, bv.y, bv.z, bv.w};
            #pragma unroll
            for (int j = 0; j < 4; ++j) {
                const int n = q * 4 + j;
                const float a = __expf(dlt * Adn[n]);
                h[n] = a * h[n] + du * bs[j];
                ap[n] *= a;
            }
        }
    }
    const size_t idx = ((size_t)bc * DI + d) * NS;
    #pragma unroll
    for (int q = 0; q < 4; ++q) {
        *(float4*)&Aprod[idx + q * 4] =
            make_float4(ap[q*4], ap[q*4+1], ap[q*4+2], ap[q*4+3]);
        *(float4*)&Hout[idx + q * 4] =
            make_float4(h[q*4], h[q*4+1], h[q*4+2], h[q*4+3]);
    }
}

// ---------------------------------------------------------------------------
// Scan phase 2: sequential over chunks per (b,d,n) chain.  24576 threads.
// Writes chunk-entry state IN-PLACE over Aprod (read-before-write per thread).
// ---------------------------------------------------------------------------
__global__ __launch_bounds__(256) void scan_p2(
    float* __restrict__ Aprod, const float* __restrict__ Hout)
{
    int gid = blockIdx.x * 256 + threadIdx.x;   // (b*DI + d)*NS + n
    int n = gid & 15;
    int d = (gid >> 4) % DI;
    int b = gid / (DI * NS);
    float hin = 0.f;
    for (int c = 0; c < NC; ++c) {
        size_t idx = (((size_t)(b * NC + c)) * DI + d) * NS + n;
        float ap = Aprod[idx];
        float ho = Hout[idx];
        Aprod[idx] = hin;          // becomes Hin
        hin = ap * hin + ho;
    }
}

// ---------------------------------------------------------------------------
// Scan phase 3 + LayerNorm + SiLU(z) gate, fused.  Writes yin as bf16
// (sole consumer is the output MFMA GEMM).
// ---------------------------------------------------------------------------
__global__ __launch_bounds__(384) void scan_p3_ln(
    const float* __restrict__ delta, const float* __restrict__ u,
    const float* __restrict__ xdbl, const float* __restrict__ Csv,
    const float* __restrict__ Hin, const float* __restrict__ A_log,
    const float* __restrict__ Dvec, const float* __restrict__ z,
    const float* __restrict__ ln_g, const float* __restrict__ ln_b,
    unsigned short* __restrict__ yin_bf)
{
    __shared__ float red_s[2][8], red_sq[2][8];
    const int d = threadIdx.x;                 // 0..383
    const int bc = blockIdx.x;                 // b*NC + c
    const int b = bc / NC, c = bc % NC;
    const int wid = d >> 6, lane = d & 63;

    float Adn[NS], h[NS];
    #pragma unroll
    for (int n = 0; n < NS; ++n)
        Adn[n] = -__expf(A_log[d * NS + n]);
    {
        const size_t idx = ((size_t)bc * DI + d) * NS;
        #pragma unroll
        for (int q = 0; q < 4; ++q) {
            const float4 hv = *(const float4*)&Hin[idx + q * 4];
            h[q*4] = hv.x; h[q*4+1] = hv.y; h[q*4+2] = hv.z; h[q*4+3] = hv.w;
        }
    }
    const float Dd = Dvec[d];
    const float lg = ln_g[d], lb = ln_b[d];

    const int lbase = c * CH;
    for (int i = 0; i < CH; ++i) {
        const size_t roff = (size_t)(b * LL + lbase + i);
        const float dlt = delta[roff * DI + d];
        const float uu  = u[roff * DI + d];
        const float du  = dlt * uu;
        const float* rowx = xdbl + roff * XDS + 12;   // Bs cols 12..27
        const float* rowc = Csv + roff * NS;
        float acc = uu * Dd;
        #pragma unroll
        for (int q = 0; q < 4; ++q) {
            const float4 bv = *(const float4*)(rowx + q * 4);
            const float4 cv = *(const float4*)(rowc + q * 4);
            const float bs[4] = {bv.x, bv.y, bv.z, bv.w};
            const float cs[4] = {cv.x, cv.y, cv.z, cv.w};
            #pragma unroll
            for (int j = 0; j < 4; ++j) {
                const int n = q * 4 + j;
                const float a = __expf(dlt * Adn[n]);
                h[n] = a * h[n] + du * bs[j];
                acc += h[n] * cs[j];
            }
        }
        // block LayerNorm reduce over 384 d's (parity LDS double-buffer)
        float s = acc, sq = acc * acc;
        #pragma unroll
        for (int m = 1; m < 64; m <<= 1) {
            s  += __shfl_xor(s, m);
            sq += __shfl_xor(sq, m);
        }
        const int par = i & 1;
        if (lane == 0) { red_s[par][wid] = s; red_sq[par][wid] = sq; }
        __syncthreads();
        s = red_s[par][0] + red_s[par][1] + red_s[par][2]
          + red_s[par][3] + red_s[par][4] + red_s[par][5];
        sq = red_sq[par][0] + red_sq[par][1] + red_sq[par][2]
           + red_sq[par][3] + red_sq[par][4] + red_sq[par][5];
        const float mu = s * (1.f / DI);
        const float var = sq * (1.f / DI) - mu * mu;
        const float inv = rsqrtf(var + 1e-5f);
        const float yn = (acc - mu) * inv * lg + lb;
        const float zz = z[roff * DI + d];
        yin_bf[roff * DI + d] = f2bf(yn * fsilu(zz));
    }
}

// ---------------------------------------------------------------------------
extern "C" void kernel_launch(void* const* d_in, const int* in_sizes, int n_in,
                              void* d_out, int out_size, void* d_ws, size_t ws_size,
                              hipStream_t stream)
{
    const float* x      = (const float*)d_in[0];
    const float* prompt = (const float*)d_in[1];
    const float* W_in   = (const float*)d_in[2];
    const float* conv_w = (const float*)d_in[3];
    const float* conv_b = (const float*)d_in[4];
    const float* Wx     = (const float*)d_in[5];
    const float* Wdt    = (const float*)d_in[6];
    const float* b_dt   = (const float*)d_in[7];
    const float* A_log  = (const float*)d_in[8];
    const float* Dvec   = (const float*)d_in[9];
    const float* Wp     = (const float*)d_in[10];
    const float* ln_g   = (const float*)d_in[11];
    const float* ln_b   = (const float*)d_in[12];
    const float* Wout   = (const float*)d_in[13];
    float* out = (float*)d_out;

    char* ws = (char*)d_ws;
    const size_t SZ_BLD = (size_t)ROWS * DI * 4;   // 25165824 B
    float* xi    = (float*)(ws);
    float* z     = (float*)(ws + SZ_BLD);
    float* u     = (float*)(ws + 2 * SZ_BLD);
    float* delta = (float*)(ws + 3 * SZ_BLD);
    char*  p     = ws + 4 * SZ_BLD;
    unsigned short* x_bf   = (unsigned short*)p;  p += (size_t)ROWS * DM * 2;      // 6.3 MB
    unsigned short* u_bf   = (unsigned short*)p;  p += (size_t)ROWS * DI * 2;      // 12.6 MB
    float* xdbl  = (float*)p;            p += (size_t)ROWS * XDS * 4;              // 4 MB
    float* Csv   = (float*)p;            p += (size_t)ROWS * NS * 4;               // 1 MB
    float* Aprod = (float*)p;            p += (size_t)BB * NC * DI * NS * 4;       // 12.6 MB
    float* Hout  = (float*)p;            p += (size_t)BB * NC * DI * NS * 4;       // 12.6 MB
    unsigned short* WinT   = (unsigned short*)p;  p += (size_t)(2 * DI) * DM * 2;  // 288 KB
    unsigned short* WxPadT = (unsigned short*)p;  p += (size_t)XDS * DI * 2;       // 48 KB
    unsigned short* WoutT  = (unsigned short*)p;  p += (size_t)DM * DI * 2;        // 144 KB
    unsigned short* yin_bf = (unsigned short*)xi; // xi dead after conv

    // 0. bf16 conversions / transposed weight builds
    f32_to_bf16_vec<<<(ROWS * DM / 4 + 255) / 256, 256, 0, stream>>>(x, x_bf, ROWS * DM / 4);
    build_bt<<<(2 * DI * DM + 255) / 256, 256, 0, stream>>>(W_in, WinT, DM, 2 * DI, 2 * DI);
    build_bt<<<(XDS * DI + 255) / 256, 256, 0, stream>>>(Wx, WxPadT, DI, 44, XDS);
    build_bt<<<(DM * DI + 255) / 256, 256, 0, stream>>>(Wout, WoutT, DI, DM, DM);

    // 1. xz = x @ W_in, split -> xi, z   (M=16384, N=768, K=192)
    {
        dim3 g(ROWS / 64, (2 * DI) / 64);
        gemm_bf16_mfma<true><<<g, 256, 0, stream>>>(x_bf, WinT, xi, z, ROWS, 2 * DI, DM, DI);
    }
    // 2. depthwise conv + bias + SiLU -> u (f32) + u_bf (bf16)
    conv_dw_silu<<<(BB * HH * WW * 96) / 256, 256, 0, stream>>>(xi, conv_w, conv_b, u, u_bf);
    // 3a. xdbl = u @ WxPad  (M=16384, N=64, K=384)
    {
        dim3 g(ROWS / 64, 1);
        gemm_bf16_mfma<false><<<g, 256, 0, stream>>>(u_bf, WxPadT, xdbl, nullptr, ROWS, XDS, DI, 0);
    }
    // 3b. Cs (+prompt@Wp) and delta (softplus low-rank)
    post_proj<<<ROWS / 4, 256, 0, stream>>>(xdbl, prompt, Wdt, b_dt, Wp, delta, Csv);
    // 4-6. chunked selective scan (p2 writes Hin in-place over Aprod)
    scan_p1_v2<<<(BB * NC * DI) / 256, 256, 0, stream>>>(delta, u, xdbl, A_log, Aprod, Hout);
    scan_p2<<<(BB * DI * NS) / 256, 256, 0, stream>>>(Aprod, Hout);
    // 7. scan replay + LayerNorm + SiLU(z) gate -> yin_bf (reuses xi)
    scan_p3_ln<<<BB * NC, 384, 0, stream>>>(delta, u, xdbl, Csv, Aprod, A_log,
                                            Dvec, z, ln_g, ln_b, yin_bf);
    // 8. out = yin @ Wout  (M=16384, N=192, K=384)
    {
        dim3 g(ROWS / 64, DM / 64);
        gemm_bf16_mfma<false><<<g, 256, 0, stream>>>(yin_bf, WoutT, out, nullptr, ROWS, DM, DI, 0);
    }
}

// Round 6
// 288.131 us; speedup vs baseline: 1.8447x; 1.1484x over previous
//
#include <hip/hip_runtime.h>
#include <hip/hip_bf16.h>

// Problem constants
#define BB 4
#define HH 64
#define WW 64
#define LL 4096           // HH*WW
#define DM 192            // D_MODEL
#define DI 384            // D_INNER
#define NS 16             // D_STATE
#define RK 12             // DT_RANK
#define NC 128            // number of scan chunks
#define CH 32             // chunk length (NC*CH == LL)
#define ROWS 16384        // BB*LL
#define XDS 64            // xdbl row stride (44 cols padded to 64)
#define LOG2E 1.44269504f

typedef __bf16 bf16x8 __attribute__((ext_vector_type(8)));
typedef float  f32x4  __attribute__((ext_vector_type(4)));

#if defined(__has_builtin)
#if __has_builtin(__builtin_amdgcn_exp2f)
#define fexp2(x) __builtin_amdgcn_exp2f(x)
#else
#define fexp2(x) exp2f(x)
#endif
#else
#define fexp2(x) exp2f(x)
#endif

__device__ __forceinline__ float fsilu(float x) {
    return x / (1.0f + __expf(-x));
}

// f32 -> bf16 (RNE)
__device__ __forceinline__ unsigned short f2bf(float f) {
    unsigned int u = __float_as_uint(f);
    unsigned int r = (u + 0x7fffu + ((u >> 16) & 1u)) >> 16;
    return (unsigned short)r;
}

// ---------------------------------------------------------------------------
// Vectorized f32 -> bf16 convert (n multiple of 4)
// ---------------------------------------------------------------------------
__global__ __launch_bounds__(256) void f32_to_bf16_vec(
    const float* __restrict__ src, unsigned short* __restrict__ dst, int n4)
{
    int i = blockIdx.x * 256 + threadIdx.x;
    if (i < n4) {
        float4 v = ((const float4*)src)[i];
        ((ushort4*)dst)[i] = make_ushort4(f2bf(v.x), f2bf(v.y), f2bf(v.z), f2bf(v.w));
    }
}

// ---------------------------------------------------------------------------
// Build transposed bf16 weight: src (K x Nsrc f32) -> dst (Nrows x K bf16),
// rows n >= Nsrc are zero (padding).
// ---------------------------------------------------------------------------
__global__ __launch_bounds__(256) void build_bt(
    const float* __restrict__ src, unsigned short* __restrict__ dst,
    int K, int Nsrc, int Nrows)
{
    int idx = blockIdx.x * 256 + threadIdx.x;
    if (idx >= Nrows * K) return;
    int n = idx / K, k = idx % K;
    dst[idx] = (n < Nsrc) ? f2bf(src[k * Nsrc + n]) : (unsigned short)0;
}

// ---------------------------------------------------------------------------
// bf16 MFMA GEMM: C(MxN f32) = A(MxK bf16) * BT^T (BT is N x K bf16).
// 64x64 tile, BK=32. 256 thr = 4 waves (2x2), each wave 32x32 via 2x2
// mfma_f32_16x16x32_bf16 fragments. LDS row stride 80B (2-way bank alias).
// ---------------------------------------------------------------------------
template<bool SPLIT>
__global__ __launch_bounds__(256) void gemm_bf16_mfma(
    const unsigned short* __restrict__ A, const unsigned short* __restrict__ BT,
    float* __restrict__ C0, float* __restrict__ C1,
    int M, int N, int K, int halfN)
{
    __shared__ __align__(16) char lds[64 * 80 * 2];
    char* As = lds;
    char* Bs = lds + 64 * 80;
    const int tid = threadIdx.x;
    const int w = tid >> 6, lane = tid & 63;
    const int wm = w >> 1, wn = w & 1;
    const int row0 = blockIdx.x * 64, col0 = blockIdx.y * 64;
    const int r = tid >> 2, cch = tid & 3;
    const int l15 = lane & 15, k8 = lane >> 4;

    f32x4 acc[2][2] = {};
    for (int k0 = 0; k0 < K; k0 += 32) {
        *(float4*)(As + r * 80 + cch * 16) =
            *(const float4*)(A + (size_t)(row0 + r) * K + k0 + cch * 8);
        *(float4*)(Bs + r * 80 + cch * 16) =
            *(const float4*)(BT + (size_t)(col0 + r) * K + k0 + cch * 8);
        __syncthreads();
        bf16x8 a0 = *(const bf16x8*)(As + (wm * 32 +      l15) * 80 + k8 * 16);
        bf16x8 a1 = *(const bf16x8*)(As + (wm * 32 + 16 + l15) * 80 + k8 * 16);
        bf16x8 b0 = *(const bf16x8*)(Bs + (wn * 32 +      l15) * 80 + k8 * 16);
        bf16x8 b1 = *(const bf16x8*)(Bs + (wn * 32 + 16 + l15) * 80 + k8 * 16);
        acc[0][0] = __builtin_amdgcn_mfma_f32_16x16x32_bf16(a0, b0, acc[0][0], 0, 0, 0);
        acc[0][1] = __builtin_amdgcn_mfma_f32_16x16x32_bf16(a0, b1, acc[0][1], 0, 0, 0);
        acc[1][0] = __builtin_amdgcn_mfma_f32_16x16x32_bf16(a1, b0, acc[1][0], 0, 0, 0);
        acc[1][1] = __builtin_amdgcn_mfma_f32_16x16x32_bf16(a1, b1, acc[1][1], 0, 0, 0);
        __syncthreads();
    }

    float* Cw;
    int cbase, cstride;
    if (SPLIT) {
        cstride = halfN;
        if (col0 < halfN) { Cw = C0; cbase = col0; }
        else              { Cw = C1; cbase = col0 - halfN; }
    } else {
        Cw = C0; cbase = col0; cstride = N;
    }
    #pragma unroll
    for (int fm = 0; fm < 2; ++fm)
        #pragma unroll
        for (int fn = 0; fn < 2; ++fn)
            #pragma unroll
            for (int reg = 0; reg < 4; ++reg) {
                int row = row0 + wm * 32 + fm * 16 + k8 * 4 + reg;
                int col = cbase + wn * 32 + fn * 16 + l15;
                Cw[(size_t)row * cstride + col] = acc[fm][fn][reg];
            }
}

// ---------------------------------------------------------------------------
// Depthwise 3x3 conv (channel-last), bias + SiLU -> u (f32) + u_bf (bf16)
// ---------------------------------------------------------------------------
__global__ __launch_bounds__(256) void conv_dw_silu(
    const float* __restrict__ xi, const float* __restrict__ conv_w,
    const float* __restrict__ conv_b, float* __restrict__ u,
    unsigned short* __restrict__ u_bf)
{
    int idx = blockIdx.x * 256 + threadIdx.x;   // total BB*HH*WW*96
    int c4 = idx % 96;
    int rest = idx / 96;
    int w = rest % WW; rest /= WW;
    int h = rest % HH;
    int b = rest / HH;
    int c = c4 * 4;

    float wgt[4][9];
    #pragma unroll
    for (int q = 0; q < 4; ++q)
        #pragma unroll
        for (int t = 0; t < 9; ++t)
            wgt[q][t] = conv_w[(c + q) * 9 + t];

    float4 acc = *(const float4*)&conv_b[c];
    #pragma unroll
    for (int kh = 0; kh < 3; ++kh) {
        int hh = h + kh - 1;
        if ((unsigned)hh >= HH) continue;
        #pragma unroll
        for (int kw = 0; kw < 3; ++kw) {
            int ww = w + kw - 1;
            if ((unsigned)ww >= WW) continue;
            const float4 xv = *(const float4*)&xi[(((size_t)(b * HH + hh)) * WW + ww) * DI + c];
            int t = kh * 3 + kw;
            acc.x += xv.x * wgt[0][t];
            acc.y += xv.y * wgt[1][t];
            acc.z += xv.z * wgt[2][t];
            acc.w += xv.w * wgt[3][t];
        }
    }
    acc.x = fsilu(acc.x); acc.y = fsilu(acc.y);
    acc.z = fsilu(acc.z); acc.w = fsilu(acc.w);
    size_t off = (((size_t)b * LL) + h * WW + w) * DI + c;
    *(float4*)&u[off] = acc;
    *(ushort4*)&u_bf[off] = make_ushort4(f2bf(acc.x), f2bf(acc.y), f2bf(acc.z), f2bf(acc.w));
}

// ---------------------------------------------------------------------------
// post_proj: one wave per row.
// ---------------------------------------------------------------------------
__global__ __launch_bounds__(256) void post_proj(
    const float* __restrict__ xdbl, const float* __restrict__ prompt,
    const float* __restrict__ Wdt, const float* __restrict__ b_dt,
    const float* __restrict__ Wp,
    float* __restrict__ delta, float* __restrict__ Csv)
{
    const int wid = threadIdx.x >> 6, lane = threadIdx.x & 63;
    const int row = blockIdx.x * 4 + wid;

    const float4* dp = (const float4*)&xdbl[(size_t)row * XDS];
    const float4 d0 = dp[0], d1 = dp[1], d2 = dp[2];
    const float dtr[RK] = {d0.x, d0.y, d0.z, d0.w, d1.x, d1.y, d1.z, d1.w,
                           d2.x, d2.y, d2.z, d2.w};

    const int n16 = lane & 15, g = lane >> 4;
    const float* prow = prompt + (size_t)row * DM + g * 48;
    float pw = 0.f;
    #pragma unroll
    for (int cc = 0; cc < 48; cc += 4) {
        const float4 p4 = *(const float4*)&prow[cc];
        const int c = g * 48 + cc;
        pw += p4.x * Wp[(c    ) * NS + n16];
        pw += p4.y * Wp[(c + 1) * NS + n16];
        pw += p4.z * Wp[(c + 2) * NS + n16];
        pw += p4.w * Wp[(c + 3) * NS + n16];
    }
    pw += __shfl_xor(pw, 16);
    pw += __shfl_xor(pw, 32);
    if (lane < 16)
        Csv[(size_t)row * NS + lane] = xdbl[(size_t)row * XDS + 28 + lane] + pw;

    #pragma unroll
    for (int jj = 0; jj < 6; ++jj) {
        int dch = jj * 64 + lane;
        float acc = b_dt[dch];
        #pragma unroll
        for (int r = 0; r < RK; ++r) acc += dtr[r] * Wdt[r * DI + dch];
        delta[(size_t)row * DI + dch] = (acc > 20.f) ? acc : log1pf(__expf(acc));
    }
}

// ---------------------------------------------------------------------------
// Scan phase 1 v3: thread per (b,chunk,d), 16 n-states in registers,
// 1-deep register prefetch of next step's (delta, u, Bs), native exp2.
// NOTE: prefetch reads one row past the chunk (mapped ws memory, value unused
// on last iteration).
// ---------------------------------------------------------------------------
__global__ __launch_bounds__(256) void scan_p1_v3(
    const float* __restrict__ delta, const float* __restrict__ u,
    const float* __restrict__ xdbl, const float* __restrict__ A_log,
    float* __restrict__ Aprod, float* __restrict__ Hout)
{
    const int g = blockIdx.x * 256 + threadIdx.x;   // bc*DI + d
    const int d = g % DI;
    const int bc = g / DI;                           // b*NC + c
    const int b = bc / NC, c = bc % NC;

    float Adn[NS], h[NS], ap[NS];
    #pragma unroll
    for (int n = 0; n < NS; ++n) {
        Adn[n] = -__expf(A_log[d * NS + n]) * LOG2E;   // log2(e) folded
        h[n] = 0.f;
        ap[n] = 1.f;
    }
    const size_t rbase = (size_t)(b * LL + c * CH);
    const float* dp = delta + rbase * DI + d;
    const float* up = u     + rbase * DI + d;
    const float* xp = xdbl  + rbase * XDS + 12;   // Bs cols 12..27

    float dlt = dp[0], uu = up[0];
    float4 bb0 = *(const float4*)(xp + 0), bb1 = *(const float4*)(xp + 4);
    float4 bb2 = *(const float4*)(xp + 8), bb3 = *(const float4*)(xp + 12);

    for (int i = 0; i < CH; ++i) {
        // prefetch step i+1 (OOB-by-one on last iter: mapped, unused)
        const float dlt_n = dp[(i + 1) * DI];
        const float uu_n  = up[(i + 1) * DI];
        const float* xn = xp + (i + 1) * XDS;
        const float4 bn0 = *(const float4*)(xn + 0), bn1 = *(const float4*)(xn + 4);
        const float4 bn2 = *(const float4*)(xn + 8), bn3 = *(const float4*)(xn + 12);

        const float du = dlt * uu;
        const float bs[NS] = {bb0.x, bb0.y, bb0.z, bb0.w, bb1.x, bb1.y, bb1.z, bb1.w,
                              bb2.x, bb2.y, bb2.z, bb2.w, bb3.x, bb3.y, bb3.z, bb3.w};
        #pragma unroll
        for (int n = 0; n < NS; ++n) {
            const float a = fexp2(dlt * Adn[n]);
            h[n] = a * h[n] + du * bs[n];
            ap[n] *= a;
        }
        dlt = dlt_n; uu = uu_n;
        bb0 = bn0; bb1 = bn1; bb2 = bn2; bb3 = bn3;
    }
    const size_t idx = ((size_t)bc * DI + d) * NS;
    #pragma unroll
    for (int q = 0; q < 4; ++q) {
        *(float4*)&Aprod[idx + q * 4] =
            make_float4(ap[q*4], ap[q*4+1], ap[q*4+2], ap[q*4+3]);
        *(float4*)&Hout[idx + q * 4] =
            make_float4(h[q*4], h[q*4+1], h[q*4+2], h[q*4+3]);
    }
}

// ---------------------------------------------------------------------------
// Scan phase 2: sequential over chunks per (b,d,n), 1-deep prefetch.
// Writes chunk-entry state IN-PLACE over Aprod.
// ---------------------------------------------------------------------------
__global__ __launch_bounds__(256) void scan_p2(
    float* __restrict__ Aprod, const float* __restrict__ Hout)
{
    const int gid = blockIdx.x * 256 + threadIdx.x;   // (b*DI + d)*NS + n
    const int dn = gid % (DI * NS);
    const int b  = gid / (DI * NS);
    const size_t base = (size_t)b * NC * DI * NS + dn;
    const size_t cstride = (size_t)DI * NS;

    float hin = 0.f;
    float ap = Aprod[base], ho = Hout[base];
    for (int c = 0; c < NC; ++c) {
        const size_t idx = base + (size_t)c * cstride;
        const float ap_n = Aprod[idx + cstride];   // OOB-by-one on last: mapped
        const float ho_n = Hout[idx + cstride];
        Aprod[idx] = hin;          // becomes Hin
        hin = ap * hin + ho;
        ap = ap_n; ho = ho_n;
    }
}

// ---------------------------------------------------------------------------
// Scan phase 3 + LayerNorm + SiLU(z) gate, fused; 1-deep prefetch of
// (delta, u, z, Bs, Cs); native exp2; writes yin as bf16.
// ---------------------------------------------------------------------------
__global__ __launch_bounds__(384) void scan_p3_ln(
    const float* __restrict__ delta, const float* __restrict__ u,
    const float* __restrict__ xdbl, const float* __restrict__ Csv,
    const float* __restrict__ Hin, const float* __restrict__ A_log,
    const float* __restrict__ Dvec, const float* __restrict__ z,
    const float* __restrict__ ln_g, const float* __restrict__ ln_b,
    unsigned short* __restrict__ yin_bf)
{
    __shared__ float red_s[2][8], red_sq[2][8];
    const int d = threadIdx.x;                 // 0..383
    const int bc = blockIdx.x;                 // b*NC + c
    const int b = bc / NC, c = bc % NC;
    const int wid = d >> 6, lane = d & 63;

    float Adn[NS], h[NS];
    #pragma unroll
    for (int n = 0; n < NS; ++n)
        Adn[n] = -__expf(A_log[d * NS + n]) * LOG2E;
    {
        const size_t idx = ((size_t)bc * DI + d) * NS;
        #pragma unroll
        for (int q = 0; q < 4; ++q) {
            const float4 hv = *(const float4*)&Hin[idx + q * 4];
            h[q*4] = hv.x; h[q*4+1] = hv.y; h[q*4+2] = hv.z; h[q*4+3] = hv.w;
        }
    }
    const float Dd = Dvec[d];
    const float lg = ln_g[d], lb = ln_b[d];

    const size_t rbase = (size_t)(b * LL + c * CH);
    const float* dp = delta + rbase * DI + d;
    const float* up = u     + rbase * DI + d;
    const float* zp = z     + rbase * DI + d;
    const float* xp = xdbl  + rbase * XDS + 12;
    const float* cp = Csv   + rbase * NS;
    unsigned short* yp = yin_bf + rbase * DI + d;

    float dlt = dp[0], uu = up[0], zz = zp[0];
    float4 bb0 = *(const float4*)(xp + 0), bb1 = *(const float4*)(xp + 4);
    float4 bb2 = *(const float4*)(xp + 8), bb3 = *(const float4*)(xp + 12);
    float4 cc0 = *(const float4*)(cp + 0), cc1 = *(const float4*)(cp + 4);
    float4 cc2 = *(const float4*)(cp + 8), cc3 = *(const float4*)(cp + 12);

    for (int i = 0; i < CH; ++i) {
        // prefetch step i+1 (OOB-by-one on last iter: mapped, unused)
        const float dlt_n = dp[(i + 1) * DI];
        const float uu_n  = up[(i + 1) * DI];
        const float zz_n  = zp[(i + 1) * DI];
        const float* xn = xp + (i + 1) * XDS;
        const float* cn = cp + (i + 1) * NS;
        const float4 bn0 = *(const float4*)(xn + 0), bn1 = *(const float4*)(xn + 4);
        const float4 bn2 = *(const float4*)(xn + 8), bn3 = *(const float4*)(xn + 12);
        const float4 cn0 = *(const float4*)(cn + 0), cn1 = *(const float4*)(cn + 4);
        const float4 cn2 = *(const float4*)(cn + 8), cn3 = *(const float4*)(cn + 12);

        const float du = dlt * uu;
        const float bs[NS] = {bb0.x, bb0.y, bb0.z, bb0.w, bb1.x, bb1.y, bb1.z, bb1.w,
                              bb2.x, bb2.y, bb2.z, bb2.w, bb3.x, bb3.y, bb3.z, bb3.w};
        const float cs[NS] = {cc0.x, cc0.y, cc0.z, cc0.w, cc1.x, cc1.y, cc1.z, cc1.w,
                              cc2.x, cc2.y, cc2.z, cc2.w, cc3.x, cc3.y, cc3.z, cc3.w};
        float acc = uu * Dd;
        #pragma unroll
        for (int n = 0; n < NS; ++n) {
            const float a = fexp2(dlt * Adn[n]);
            h[n] = a * h[n] + du * bs[n];
            acc += h[n] * cs[n];
        }
        // block LayerNorm reduce over 384 d's (parity LDS double-buffer)
        float s = acc, sq = acc * acc;
        #pragma unroll
        for (int m = 1; m < 64; m <<= 1) {
            s  += __shfl_xor(s, m);
            sq += __shfl_xor(sq, m);
        }
        const int par = i & 1;
        if (lane == 0) { red_s[par][wid] = s; red_sq[par][wid] = sq; }
        __syncthreads();
        s = red_s[par][0] + red_s[par][1] + red_s[par][2]
          + red_s[par][3] + red_s[par][4] + red_s[par][5];
        sq = red_sq[par][0] + red_sq[par][1] + red_sq[par][2]
           + red_sq[par][3] + red_sq[par][4] + red_sq[par][5];
        const float mu = s * (1.f / DI);
        const float var = sq * (1.f / DI) - mu * mu;
        const float inv = rsqrtf(var + 1e-5f);
        const float yn = (acc - mu) * inv * lg + lb;
        yp[(size_t)i * DI] = f2bf(yn * fsilu(zz));

        dlt = dlt_n; uu = uu_n; zz = zz_n;
        bb0 = bn0; bb1 = bn1; bb2 = bn2; bb3 = bn3;
        cc0 = cn0; cc1 = cn1; cc2 = cn2; cc3 = cn3;
    }
}

// ---------------------------------------------------------------------------
extern "C" void kernel_launch(void* const* d_in, const int* in_sizes, int n_in,
                              void* d_out, int out_size, void* d_ws, size_t ws_size,
                              hipStream_t stream)
{
    const float* x      = (const float*)d_in[0];
    const float* prompt = (const float*)d_in[1];
    const float* W_in   = (const float*)d_in[2];
    const float* conv_w = (const float*)d_in[3];
    const float* conv_b = (const float*)d_in[4];
    const float* Wx     = (const float*)d_in[5];
    const float* Wdt    = (const float*)d_in[6];
    const float* b_dt   = (const float*)d_in[7];
    const float* A_log  = (const float*)d_in[8];
    const float* Dvec   = (const float*)d_in[9];
    const float* Wp     = (const float*)d_in[10];
    const float* ln_g   = (const float*)d_in[11];
    const float* ln_b   = (const float*)d_in[12];
    const float* Wout   = (const float*)d_in[13];
    float* out = (float*)d_out;

    char* ws = (char*)d_ws;
    const size_t SZ_BLD = (size_t)ROWS * DI * 4;   // 25165824 B
    float* xi    = (float*)(ws);
    float* z     = (float*)(ws + SZ_BLD);
    float* u     = (float*)(ws + 2 * SZ_BLD);
    float* delta = (float*)(ws + 3 * SZ_BLD);
    char*  p     = ws + 4 * SZ_BLD;
    unsigned short* x_bf   = (unsigned short*)p;  p += (size_t)ROWS * DM * 2;      // 6.3 MB
    unsigned short* u_bf   = (unsigned short*)p;  p += (size_t)ROWS * DI * 2;      // 12.6 MB
    float* xdbl  = (float*)p;            p += (size_t)ROWS * XDS * 4;              // 4 MB
    float* Csv   = (float*)p;            p += (size_t)ROWS * NS * 4;               // 1 MB
    float* Aprod = (float*)p;            p += (size_t)BB * NC * DI * NS * 4;       // 12.6 MB
    float* Hout  = (float*)p;            p += (size_t)BB * NC * DI * NS * 4;       // 12.6 MB
    unsigned short* WinT   = (unsigned short*)p;  p += (size_t)(2 * DI) * DM * 2;  // 288 KB
    unsigned short* WxPadT = (unsigned short*)p;  p += (size_t)XDS * DI * 2;       // 48 KB
    unsigned short* WoutT  = (unsigned short*)p;  p += (size_t)DM * DI * 2;        // 144 KB
    unsigned short* yin_bf = (unsigned short*)xi; // xi dead after conv

    // 0. bf16 conversions / transposed weight builds
    f32_to_bf16_vec<<<(ROWS * DM / 4 + 255) / 256, 256, 0, stream>>>(x, x_bf, ROWS * DM / 4);
    build_bt<<<(2 * DI * DM + 255) / 256, 256, 0, stream>>>(W_in, WinT, DM, 2 * DI, 2 * DI);
    build_bt<<<(XDS * DI + 255) / 256, 256, 0, stream>>>(Wx, WxPadT, DI, 44, XDS);
    build_bt<<<(DM * DI + 255) / 256, 256, 0, stream>>>(Wout, WoutT, DI, DM, DM);

    // 1. xz = x @ W_in, split -> xi, z   (M=16384, N=768, K=192)
    {
        dim3 g(ROWS / 64, (2 * DI) / 64);
        gemm_bf16_mfma<true><<<g, 256, 0, stream>>>(x_bf, WinT, xi, z, ROWS, 2 * DI, DM, DI);
    }
    // 2. depthwise conv + bias + SiLU -> u (f32) + u_bf (bf16)
    conv_dw_silu<<<(BB * HH * WW * 96) / 256, 256, 0, stream>>>(xi, conv_w, conv_b, u, u_bf);
    // 3a. xdbl = u @ WxPad  (M=16384, N=64, K=384)
    {
        dim3 g(ROWS / 64, 1);
        gemm_bf16_mfma<false><<<g, 256, 0, stream>>>(u_bf, WxPadT, xdbl, nullptr, ROWS, XDS, DI, 0);
    }
    // 3b. Cs (+prompt@Wp) and delta (softplus low-rank)
    post_proj<<<ROWS / 4, 256, 0, stream>>>(xdbl, prompt, Wdt, b_dt, Wp, delta, Csv);
    // 4-6. chunked selective scan (p2 writes Hin in-place over Aprod)
    scan_p1_v3<<<(BB * NC * DI) / 256, 256, 0, stream>>>(delta, u, xdbl, A_log, Aprod, Hout);
    scan_p2<<<(BB * DI * NS) / 256, 256, 0, stream>>>(Aprod, Hout);
    // 7. scan replay + LayerNorm + SiLU(z) gate -> yin_bf (reuses xi)
    scan_p3_ln<<<BB * NC, 384, 0, stream>>>(delta, u, xdbl, Csv, Aprod, A_log,
                                            Dvec, z, ln_g, ln_b, yin_bf);
    // 8. out = yin @ Wout  (M=16384, N=192, K=384)
    {
        dim3 g(ROWS / 64, DM / 64);
        gemm_bf16_mfma<false><<<g, 256, 0, stream>>>(yin_bf, WoutT, out, nullptr, ROWS, DM, DI, 0);
    }
}